// Round 13
// baseline (858.695 us; speedup 1.0000x reference)
//
#include <hip/hip_runtime.h>
#include <cstdint>
#include <cstddef>

// ---------------------------------------------------------------------------
// TransformerEncoderLayer on MI355X (gfx950).
// Pre-gate GEMMs: f16 hi/lo split MFMA (3 mfma/product) — validated bit-equal
// to fp32 routing. QKV/out_proj: double-buffered global_load_lds pipeline
// (stage t+1 BEFORE compute t, ONE __syncthreads per K-step — its vmcnt(0)
// drain lands after ~300cyc of MFMA, hiding load latency; T3 2-phase recipe).
// Attention: fused flash, swapped QK^T + in-register softmax + reg->reg P.
// Gate RNG: partitionable threefry, b1^b2 (VERIFIED round 5 — DO NOT TOUCH).
// MoE: bucketed per-expert f16 MFMA (128x64 core).
// ---------------------------------------------------------------------------

typedef _Float16 h16;
typedef h16 h16x8 __attribute__((ext_vector_type(8)));
typedef h16 h16x4 __attribute__((ext_vector_type(4)));
typedef __fp16 fp16x2 __attribute__((ext_vector_type(2)));   // cvt_pkrtz native type
typedef float f32x4 __attribute__((ext_vector_type(4)));
typedef uint32_t u32;

#define DM 1024
#define NH 16
#define HD 64
#define SEQ 1024
#define BB 8
#define BS (BB*SEQ)      /* 8192 tokens */
#define NBH (BB*NH)      /* 128 (b,h) pairs */
#define NE 4
#define DFE 1024
#define QB 64            /* query rows per attention chunk */
#define NCHUNK (SEQ/QB)  /* 16 */
#define LDK 40           /* LDS stride (h16) for MoE core slabs */
#define SLDA 32          /* linear LDS stride (h16) for gload_lds slabs */
#define FLD 72           /* LDS stride for 64-wide flash tiles (64+8 pad) */
#define NPOS (68*128)    /* 8704: bucket capacity, 128-padded per expert */

#define MFMA16(a,b,c) __builtin_amdgcn_mfma_f32_16x16x32_f16(a,b,c,0,0,0)

// ---- workspace layout (bytes). E = one h16 plane of [8192][1024]. ----
static constexpr size_t E = (size_t)BS*DM*2;            // 16,777,216
static constexpr size_t OFF_QKH = 0;                    // qk split (dead after qkv)
static constexpr size_t OFF_QKL = E;
static constexpr size_t OFF_SRCH= 2*E;
static constexpr size_t OFF_SRCL= 3*E;
static constexpr size_t OFF_W3H = 4*E;
static constexpr size_t OFF_W3L = 4*E + (size_t)3*DM*DM*2;
static constexpr size_t OFF_WOH = 4*E + (size_t)6*DM*DM*2;
static constexpr size_t OFF_WOL = 4*E + (size_t)7*DM*DM*2;   // ends at 5E
static constexpr size_t OFF_QH  = 5*E;                  // Q,K [bh][s][d]; V^T [bh][d][s]
static constexpr size_t OFF_QL  = 6*E;
static constexpr size_t OFF_KH  = 7*E;
static constexpr size_t OFF_KL  = 8*E;
static constexpr size_t OFF_VH  = 9*E;
static constexpr size_t OFF_VL  = 10*E;
static constexpr size_t OFF_OH  = 0;                    // after flash (qk dead)
static constexpr size_t OFF_OL  = E;
static constexpr size_t OFF_ATT = 2*E;                  // fp32 (src splits dead)
static constexpr size_t OFF_X   = 5*E;                  // fp32 2E (Q,Ql dead)
static constexpr size_t OFF_XH  = 7*E;                  // f16 x*16 (Kh dead)
static constexpr size_t OFF_W1H = 8*E;                  // f16 (Kl dead)
static constexpr size_t OFF_W2H = 8*E + (size_t)NE*DFE*DM*2;  // ends at 9E
static constexpr size_t OFF_HH  = 9*E;                  // bucket h f16 [NPOS][1024] (V dead)
static constexpr size_t OFF_Y   = 11*E;                 // fp32 2E
static constexpr size_t OFF_CHOSEN = 13*E;
static constexpr size_t OFF_COUNTS = 13*E + 32768;
static constexpr size_t OFF_CURSOR = OFF_COUNTS + 16;
static constexpr size_t OFF_EOFF   = OFF_CURSOR + 16;
static constexpr size_t OFF_PLIST  = OFF_EOFF + 16;
static constexpr size_t WS_NEEDED  = OFF_PLIST + (size_t)NPOS*4;

// ---------------------------------------------------------------------------
__device__ __forceinline__ void store_split(h16* H, h16* L, size_t idx, float v) {
  h16 h = (h16)v;
  H[idx] = h;
  L[idx] = (h16)((v - (float)h) * 4096.0f);
}

__device__ __forceinline__ float wave_sum(float v) {
  #pragma unroll
  for (int o = 32; o; o >>= 1) v += __shfl_xor(v, o);
  return v;
}

// pack two floats to f16x2 (RTZ) and return the u32 word + the two f16 values
__device__ __forceinline__ u32 pk2(float a, float b, float& fa, float& fb) {
  union { fp16x2 h; u32 w; } u;
  u.h = __builtin_amdgcn_cvt_pkrtz(a, b);
  fa = (float)u.h[0];
  fb = (float)u.h[1];
  return u.w;
}
__device__ __forceinline__ u32 pk2w(float a, float b) {
  union { fp16x2 h; u32 w; } u;
  u.h = __builtin_amdgcn_cvt_pkrtz(a, b);
  return u.w;
}

// async global->LDS, 16B per lane; LDS dest = uniform base + lane*16
__device__ __forceinline__ void gload16(const void* g, void* l) {
  __builtin_amdgcn_global_load_lds(
      (const __attribute__((address_space(1))) u32*)g,
      (__attribute__((address_space(3))) u32*)l, 16, 0, 0);
}

// ---------------------------------------------------------------------------
// 128(M)x64(N) split-f16 MFMA core, DOUBLE-BUFFERED global_load_lds pipeline.
// Per K-step: issue 6 gload16 for tile t+1 into buf^1, then ds_read+MFMA tile
// t from buf, then ONE __syncthreads (emits s_waitcnt vmcnt(0) lgkmcnt(0) +
// s_barrier) -> the t+1 load latency hides under ~300cyc of compute.
// XOR source-swizzle (round 10, verified, 0 bank conflicts) kept.
// ---------------------------------------------------------------------------
__device__ __forceinline__ void gemm128x64_core(
    const h16* __restrict__ Ah, const h16* __restrict__ Al,
    const h16* __restrict__ Bh, const h16* __restrict__ Bl,
    int K, int lda, int ldb, int m0, int n0,
    f32x4 (&a1)[4][2], f32x4 (&a2)[4][2], h16* lds)
{
  constexpr int BUF = (2*128 + 2*64)*SLDA;   // 12288 h16 per buffer
  const int tid = threadIdx.x, lane = tid & 63, wid = tid >> 6;
  const int wr = (wid >> 1) * 64, wc = (wid & 1) * 32;
  const int lr16 = lane >> 2, lgrp = lane & 3;
  const int rA0 = wid*32 + lr16;
  const int rB  = wid*16 + lr16;
  const int swA = (rA0 >> 1) & 3;
  const int swB = (rB  >> 1) & 3;
  const long gA0 = (long)(m0 + rA0)      * lda + ((lgrp ^ swA) << 3);
  const long gA1 = (long)(m0 + rA0 + 16) * lda + ((lgrp ^ swA) << 3);
  const long gB  = (long)(n0 + rB)       * ldb + ((lgrp ^ swB) << 3);
  const int oA0 = (wid*32)*SLDA, oA1 = (wid*32+16)*SLDA, oB = (wid*16)*SLDA;
  const int fr = lane & 15, gi = lane >> 4;
  const int pcol = ((gi ^ ((lane >> 1) & 3)) << 3);
  const int nt = K >> 5;

  auto stage = [&](int t, int buf) {
    h16* base = lds + buf*BUF;
    h16* sAh = base;               h16* sAl = base + 128*SLDA;
    h16* sBh = base + 2*128*SLDA;  h16* sBl = base + 2*128*SLDA + 64*SLDA;
    const int k0 = t << 5;
    gload16(Ah + gA0 + k0, sAh + oA0);
    gload16(Ah + gA1 + k0, sAh + oA1);
    gload16(Al + gA0 + k0, sAl + oA0);
    gload16(Al + gA1 + k0, sAl + oA1);
    gload16(Bh + gB  + k0, sBh + oB);
    gload16(Bl + gB  + k0, sBl + oB);
  };

  stage(0, 0);
  __syncthreads();                       // tile 0 resident
  int cur = 0;
  for (int t = 0; t < nt; ++t) {
    if (t + 1 < nt) stage(t + 1, cur ^ 1);   // issue-early: hides under MFMA
    h16* base = lds + cur*BUF;
    h16* sAh = base;               h16* sAl = base + 128*SLDA;
    h16* sBh = base + 2*128*SLDA;  h16* sBl = base + 2*128*SLDA + 64*SLDA;
    h16x8 ah[4], al[4], bh[2], bl[2];
    #pragma unroll
    for (int i = 0; i < 4; ++i) {
      ah[i] = *(const h16x8*)(sAh + (wr + i*16 + fr)*SLDA + pcol);
      al[i] = *(const h16x8*)(sAl + (wr + i*16 + fr)*SLDA + pcol);
    }
    #pragma unroll
    for (int j = 0; j < 2; ++j) {
      bh[j] = *(const h16x8*)(sBh + (wc + j*16 + fr)*SLDA + pcol);
      bl[j] = *(const h16x8*)(sBl + (wc + j*16 + fr)*SLDA + pcol);
    }
    #pragma unroll
    for (int i = 0; i < 4; ++i)
      #pragma unroll
      for (int j = 0; j < 2; ++j) {
        a1[i][j] = MFMA16(ah[i], bh[j], a1[i][j]);
        a2[i][j] = MFMA16(ah[i], bl[j], a2[i][j]);
        a2[i][j] = MFMA16(al[i], bh[j], a2[i][j]);
      }
    __syncthreads();                     // drains t+1 loads + all reads of buf
    cur ^= 1;
  }
}

#define EPI_W \
  const int lane = threadIdx.x & 63, wid = threadIdx.x >> 6; \
  const int wr = (wid>>1)*64, wc = (wid&1)*32; \
  const int fr = lane & 15, rb = (lane>>4)*4;

// ---------------------------------------------------------------------------
// 128(M)x64(N) f16 single MFMA core for MoE (unchanged, validated).
// ---------------------------------------------------------------------------
template<bool GATHER>
__device__ __forceinline__ void hgemm128_core(
    const h16* __restrict__ A, const h16* __restrict__ B,
    int K, int lda, int ldb, int m0, int n0, const int* __restrict__ rowmap,
    f32x4 (&acc)[4][2], h16* lds)
{
  const int tid = threadIdx.x, lane = tid & 63, wid = tid >> 6;
  const int wr = (wid >> 1) * 64, wc = (wid & 1) * 32;
  h16* sA = lds;              // [128][LDK]
  h16* sB = lds + 128*LDK;    // [64][LDK]
  const int arow = tid >> 1, akc = (tid & 1) * 16;
  const int brow = tid >> 2, bkc = (tid & 3) * 8;
  long abase; bool aval = true;
  if (GATHER) { int t = rowmap[m0 + arow]; aval = (t >= 0);
                abase = (long)(aval ? t : 0) * lda + akc; }
  else          abase = (long)(m0 + arow) * lda + akc;
  const long bbase = (long)(n0 + brow) * ldb + bkc;
  const int fr = lane & 15, kg = (lane >> 4) << 3;
  for (int k0 = 0; k0 < K; k0 += 32) {
    __syncthreads();
    uint4 va0 = (!GATHER || aval) ? *(const uint4*)(A + abase + k0)     : make_uint4(0,0,0,0);
    uint4 va1 = (!GATHER || aval) ? *(const uint4*)(A + abase + k0 + 8) : make_uint4(0,0,0,0);
    *(uint4*)(sA + arow*LDK + akc)     = va0;
    *(uint4*)(sA + arow*LDK + akc + 8) = va1;
    *(uint4*)(sB + brow*LDK + bkc)     = *(const uint4*)(B + bbase + k0);
    __syncthreads();
    h16x8 a_[4], b_[2];
    #pragma unroll
    for (int i = 0; i < 4; ++i)
      a_[i] = *(const h16x8*)(sA + (wr + i*16 + fr)*LDK + kg);
    #pragma unroll
    for (int j = 0; j < 2; ++j)
      b_[j] = *(const h16x8*)(sB + (wc + j*16 + fr)*LDK + kg);
    #pragma unroll
    for (int i = 0; i < 4; ++i)
      #pragma unroll
      for (int j = 0; j < 2; ++j)
        acc[i][j] = MFMA16(a_[i], b_[j], acc[i][j]);
  }
}

// ---------------------------------------------------------------------------
// prep kernels
// ---------------------------------------------------------------------------
__global__ void k_zero8(int* __restrict__ p) {
  if (threadIdx.x < 8) p[threadIdx.x] = 0;   // counts[4] + cursor[4]
}

__global__ void k_split_in(const float* __restrict__ src, const float* __restrict__ pos,
                           h16* __restrict__ qkH, h16* __restrict__ qkL,
                           h16* __restrict__ sH,  h16* __restrict__ sL) {
  int i = blockIdx.x*256 + threadIdx.x;
  float4 s = ((const float4*)src)[i];
  float4 p = ((const float4*)pos)[i];
  float sv[4] = {s.x, s.y, s.z, s.w};
  float qv[4] = {s.x+p.x, s.y+p.y, s.z+p.z, s.w+p.w};
  h16x4 sh, sl, qh, ql;
  #pragma unroll
  for (int q = 0; q < 4; ++q) {
    float xs = sv[q] * 16.0f; h16 hs = (h16)xs;
    sh[q] = hs; sl[q] = (h16)((xs - (float)hs) * 4096.0f);
    float xq = qv[q] * 16.0f; h16 hq = (h16)xq;
    qh[q] = hq; ql[q] = (h16)((xq - (float)hq) * 4096.0f);
  }
  ((h16x4*)sH)[i] = sh; ((h16x4*)sL)[i] = sl;
  ((h16x4*)qkH)[i] = qh; ((h16x4*)qkL)[i] = ql;
}

__global__ void k_split2(const float* __restrict__ a,
                         h16* __restrict__ H, h16* __restrict__ L, float scale, int n4) {
  int i = blockIdx.x*256 + threadIdx.x;
  if (i >= n4) return;
  float4 v = ((const float4*)a)[i];
  float vv[4] = {v.x, v.y, v.z, v.w};
  h16x4 hv, lv;
  #pragma unroll
  for (int q = 0; q < 4; ++q) {
    float x = vv[q] * scale;
    h16 h = (h16)x;
    hv[q] = h;
    lv[q] = (h16)((x - (float)h) * 4096.0f);
  }
  ((h16x4*)H)[i] = hv;
  ((h16x4*)L)[i] = lv;
}

__global__ void k_tof16(const float* __restrict__ a, h16* __restrict__ H, float scale, int n4) {
  int i = blockIdx.x*256 + threadIdx.x;
  if (i >= n4) return;
  float4 v = ((const float4*)a)[i];
  h16x4 hv;
  hv[0] = (h16)(v.x*scale); hv[1] = (h16)(v.y*scale);
  hv[2] = (h16)(v.z*scale); hv[3] = (h16)(v.w*scale);
  ((h16x4*)H)[i] = hv;
}

// ---------------------------------------------------------------------------
// QKV projection (128x64 split MFMA tiles, dbuf gload_lds pipeline)
// ---------------------------------------------------------------------------
__global__ __launch_bounds__(256) void k_qkv(
    const h16* __restrict__ qkh, const h16* __restrict__ qkl,
    const h16* __restrict__ sh,  const h16* __restrict__ sl,
    const h16* __restrict__ Wh,  const h16* __restrict__ Wl, const float* __restrict__ bias,
    h16* __restrict__ Qh, h16* __restrict__ Ql, h16* __restrict__ Kh, h16* __restrict__ Kl,
    h16* __restrict__ Vh, h16* __restrict__ Vl)
{
  __shared__ h16 lds[2*(2*128 + 2*64)*SLDA];   // 49,152 B (double buffer)
  const int n0 = blockIdx.x*64, m0 = blockIdx.y*128;
  const bool isV = (n0 >= 2048);
  f32x4 a1[4][2] = {}; f32x4 a2[4][2] = {};
  gemm128x64_core(isV ? sh : qkh, isV ? sl : qkl, Wh, Wl,
                  1024, 1024, 1024, m0, n0, a1, a2, lds);
  EPI_W;
  #pragma unroll
  for (int i = 0; i < 4; ++i)
    #pragma unroll
    for (int j = 0; j < 2; ++j)
      #pragma unroll
      for (int r = 0; r < 4; ++r) {
        int row = m0 + wr + i*16 + rb + r;
        int col = n0 + wc + j*16 + fr;
        float c = (a1[i][j][r] + a2[i][j][r]*(1.0f/4096.0f)) * (1.0f/1024.0f) + bias[col];
        int b = row >> 10, s = row & 1023;
        int cc = col & 1023, h = cc >> 6, d = cc & 63;
        long bh = (long)b*NH + h;
        float cs = c * 16.0f;
        if (col < 1024)      store_split(Qh, Ql, (bh*SEQ + s)*HD + d, cs);
        else if (col < 2048) store_split(Kh, Kl, (bh*SEQ + s)*HD + d, cs);
        else                 store_split(Vh, Vl, (bh*HD + d)*SEQ + s, cs);
      }
}

// ---------------------------------------------------------------------------
// Fused flash attention (round 12, verified): swapped QK^T, in-reg softmax,
// reg->reg P via cvt_pkrtz + shfl.
// ---------------------------------------------------------------------------
__global__ __launch_bounds__(256) void k_attn(
    const h16* __restrict__ Qh, const h16* __restrict__ Ql,
    const h16* __restrict__ Kh, const h16* __restrict__ Kl,
    const h16* __restrict__ Vh, const h16* __restrict__ Vl,
    h16* __restrict__ Oh, h16* __restrict__ Ol)
{
  __shared__ h16 lds[4*64*FLD];   // 36,864 B (K h/l + V h/l)
  h16* sKh = lds;            h16* sKl = lds + 64*FLD;
  h16* sVh = lds + 2*64*FLD; h16* sVl = lds + 3*64*FLD;
  const int bid = blockIdx.x;                  // 0..2047
  const int swz = (bid & 7) * 256 + (bid >> 3);
  const int bh = swz >> 4;
  const int q0 = (swz & 15) * QB;
  const int tid = threadIdx.x, lane = tid & 63, w = tid >> 6;
  const int fr = lane & 15, hg = lane >> 4;   // 0..3
  const int kg = hg << 3;
  const long qbase = ((long)bh*SEQ + q0 + w*16 + fr) * HD;
  h16x8 qh[2], ql[2];
  qh[0] = *(const h16x8*)(Qh + qbase + kg);
  qh[1] = *(const h16x8*)(Qh + qbase + 32 + kg);
  ql[0] = *(const h16x8*)(Ql + qbase + kg);
  ql[1] = *(const h16x8*)(Ql + qbase + 32 + kg);
  f32x4 o1[4] = {}, o2[4] = {};      // O[q=4hg+r][d=16jd+fr]
  float mrow = -3.0e38f, lrow = 0.f; // for q-row = w*16 + fr
  const int srow = tid >> 2, skc = (tid & 3) << 4;
  const long kbase = ((long)bh*SEQ + srow) * HD + skc;
  const long vbase = ((long)bh*HD + srow) * SEQ + skc;
  const int srcA = fr + ((hg & 1) << 5);
  const int srcB = srcA + 16;
  for (int kt = 0; kt < NCHUNK; ++kt) {
    const int n0 = kt * QB;
    __syncthreads();
    {
      const long ka = kbase + (long)n0*HD;
      *(uint4*)(sKh + srow*FLD + skc)     = *(const uint4*)(Kh + ka);
      *(uint4*)(sKh + srow*FLD + skc + 8) = *(const uint4*)(Kh + ka + 8);
      *(uint4*)(sKl + srow*FLD + skc)     = *(const uint4*)(Kl + ka);
      *(uint4*)(sKl + srow*FLD + skc + 8) = *(const uint4*)(Kl + ka + 8);
      const long va = vbase + n0;
      *(uint4*)(sVh + srow*FLD + skc)     = *(const uint4*)(Vh + va);
      *(uint4*)(sVh + srow*FLD + skc + 8) = *(const uint4*)(Vh + va + 8);
      *(uint4*)(sVl + srow*FLD + skc)     = *(const uint4*)(Vl + va);
      *(uint4*)(sVl + srow*FLD + skc + 8) = *(const uint4*)(Vl + va + 8);
    }
    __syncthreads();
    f32x4 s1[4] = {}, s2[4] = {};
    #pragma unroll
    for (int ks = 0; ks < 2; ++ks)
      #pragma unroll
      for (int j = 0; j < 4; ++j) {
        h16x8 kh = *(const h16x8*)(sKh + (j*16 + fr)*FLD + ks*32 + kg);
        h16x8 kl = *(const h16x8*)(sKl + (j*16 + fr)*FLD + ks*32 + kg);
        s1[j] = MFMA16(kh, qh[ks], s1[j]);
        s2[j] = MFMA16(kh, ql[ks], s2[j]);
        s2[j] = MFMA16(kl, qh[ks], s2[j]);
      }
    float p[4][4];
    float tmax = -3.0e38f;
    #pragma unroll
    for (int j = 0; j < 4; ++j)
      #pragma unroll
      for (int r = 0; r < 4; ++r) {
        float sc = (s1[j][r] + s2[j][r]*(1.0f/4096.0f)) * (0.125f/256.0f);
        p[j][r] = sc;
        tmax = fmaxf(tmax, sc);
      }
    tmax = fmaxf(tmax, __shfl_xor(tmax, 16));
    tmax = fmaxf(tmax, __shfl_xor(tmax, 32));
    float mn = fmaxf(mrow, tmax);
    float sclf = __expf(mrow - mn);
    mrow = mn;
    float psum = 0.f;
    #pragma unroll
    for (int j = 0; j < 4; ++j)
      #pragma unroll
      for (int r = 0; r < 4; ++r) { float e = __expf(p[j][r] - mn); p[j][r] = e; psum += e; }
    psum += __shfl_xor(psum, 16);
    psum += __shfl_xor(psum, 32);
    lrow = lrow*sclf + psum;
    #pragma unroll
    for (int r = 0; r < 4; ++r) {
      float sq = __shfl(sclf, hg*4 + r);
      #pragma unroll
      for (int jd = 0; jd < 4; ++jd) { o1[jd][r] *= sq; o2[jd][r] *= sq; }
    }
    u32 hp[4][2], lp[4][2];
    #pragma unroll
    for (int j = 0; j < 4; ++j)
      #pragma unroll
      for (int rp = 0; rp < 2; ++rp) {
        float a = p[j][2*rp]   * 512.0f;
        float b = p[j][2*rp+1] * 512.0f;
        float fa, fb;
        hp[j][rp] = pk2(a, b, fa, fb);
        lp[j][rp] = pk2w((a - fa) * 4096.0f, (b - fb) * 4096.0f);
      }
    #pragma unroll
    for (int ks = 0; ks < 2; ++ks) {
      const int j0 = 2*ks, j1 = 2*ks + 1;
      u32 hA0 = (u32)__shfl((int)hp[j0][0], srcA), hA1 = (u32)__shfl((int)hp[j0][1], srcA);
      u32 hB0 = (u32)__shfl((int)hp[j0][0], srcB), hB1 = (u32)__shfl((int)hp[j0][1], srcB);
      u32 hC0 = (u32)__shfl((int)hp[j1][0], srcA), hC1 = (u32)__shfl((int)hp[j1][1], srcA);
      u32 hD0 = (u32)__shfl((int)hp[j1][0], srcB), hD1 = (u32)__shfl((int)hp[j1][1], srcB);
      u32 lA0 = (u32)__shfl((int)lp[j0][0], srcA), lA1 = (u32)__shfl((int)lp[j0][1], srcA);
      u32 lB0 = (u32)__shfl((int)lp[j0][0], srcB), lB1 = (u32)__shfl((int)lp[j0][1], srcB);
      u32 lC0 = (u32)__shfl((int)lp[j1][0], srcA), lC1 = (u32)__shfl((int)lp[j1][1], srcA);
      u32 lD0 = (u32)__shfl((int)lp[j1][0], srcB), lD1 = (u32)__shfl((int)lp[j1][1], srcB);
      const bool hij = (hg & 2) != 0;
      union { u32 w[4]; h16x8 v; } pa, pb;
      pa.w[0] = hij ? hC0 : hA0;  pa.w[1] = hij ? hC1 : hA1;
      pa.w[2] = hij ? hD0 : hB0;  pa.w[3] = hij ? hD1 : hB1;
      pb.w[0] = hij ? lC0 : lA0;  pb.w[1] = hij ? lC1 : lA1;
      pb.w[2] = hij ? lD0 : lB0;  pb.w[3] = hij ? lD1 : lB1;
      #pragma unroll
      for (int jd = 0; jd < 4; ++jd) {
        h16x8 vh = *(const h16x8*)(sVh + (jd*16 + fr)*FLD + ks*32 + kg);
        h16x8 vl = *(const h16x8*)(sVl + (jd*16 + fr)*FLD + ks*32 + kg);
        o1[jd] = MFMA16(pa.v, vh, o1[jd]);
        o2[jd] = MFMA16(pa.v, vl, o2[jd]);
        o2[jd] = MFMA16(pb.v, vh, o2[jd]);
      }
    }
  }
  float lq[4];
  #pragma unroll
  for (int r = 0; r < 4; ++r) lq[r] = __shfl(lrow, hg*4 + r);
  const int b = bh >> 4, h = bh & 15;
  #pragma unroll
  for (int jd = 0; jd < 4; ++jd)
    #pragma unroll
    for (int r = 0; r < 4; ++r) {
      int qrow = q0 + w*16 + hg*4 + r;
      int d = jd*16 + fr;
      float ov = (o1[jd][r] + o2[jd][r]*(1.0f/4096.0f)) / (512.0f*16.0f*lq[r]);
      store_split(Oh, Ol, ((long)b*SEQ + qrow)*DM + h*HD + d, ov*16.0f);
    }
}

// out_proj (128x64 split, dbuf gload_lds pipeline): attn = O.Wo^T + bo, fp32
__global__ __launch_bounds__(256) void k_out(
    const h16* __restrict__ Oh, const h16* __restrict__ Ol,
    const h16* __restrict__ Wh, const h16* __restrict__ Wl,
    const float* __restrict__ bias, float* __restrict__ attn)
{
  __shared__ h16 lds[2*(2*128 + 2*64)*SLDA];
  const int n0 = blockIdx.x*64, m0 = blockIdx.y*128;
  f32x4 a1[4][2] = {}; f32x4 a2[4][2] = {};
  gemm128x64_core(Oh, Ol, Wh, Wl, 1024, 1024, 1024, m0, n0, a1, a2, lds);
  EPI_W;
  #pragma unroll
  for (int i = 0; i < 4; ++i)
    #pragma unroll
    for (int j = 0; j < 2; ++j)
      #pragma unroll
      for (int r = 0; r < 4; ++r) {
        int row = m0 + wr + i*16 + rb + r;
        int col = n0 + wc + j*16 + fr;
        attn[(long)row*DM + col] =
            (a1[i][j][r] + a2[i][j][r]*(1.0f/4096.0f)) * (1.0f/1024.0f) + bias[col];
      }
}

// LayerNorm of (A + Badd): optional fp32 out, f16(x*16) out, direct out
__global__ __launch_bounds__(256) void k_ln(
    const float* __restrict__ A, const float* __restrict__ Badd,
    const float* __restrict__ g, const float* __restrict__ be,
    float* __restrict__ xout, h16* __restrict__ xh, float* __restrict__ dout)
{
  int wave = threadIdx.x >> 6, lane = threadIdx.x & 63;
  long row = (long)blockIdx.x*4 + wave;
  const float* ar = A + row*DM; const float* br = Badd + row*DM;
  float v[16]; float s = 0.0f;
  #pragma unroll
  for (int p = 0; p < 4; ++p) {
    int d = p*256 + lane*4;
    float4 a = *(const float4*)(ar + d);
    float4 b = *(const float4*)(br + d);
    float t0=a.x+b.x, t1=a.y+b.y, t2=a.z+b.z, t3=a.w+b.w;
    v[4*p+0]=t0; v[4*p+1]=t1; v[4*p+2]=t2; v[4*p+3]=t3;
    s += t0+t1+t2+t3;
  }
  s = wave_sum(s);
  float m = s * (1.0f/1024.0f);
  float q = 0.0f;
  #pragma unroll
  for (int i = 0; i < 16; ++i) { float dd = v[i]-m; q += dd*dd; }
  q = wave_sum(q);
  float rs = (float)(1.0 / sqrt((double)(q * (1.0f/1024.0f) + 1e-5f)));
  #pragma unroll
  for (int p = 0; p < 4; ++p) {
    int d = p*256 + lane*4;
    float4 gv = *(const float4*)(g + d);
    float4 bv = *(const float4*)(be + d);
    float y0 = (v[4*p+0]-m)*rs*gv.x + bv.x;
    float y1 = (v[4*p+1]-m)*rs*gv.y + bv.y;
    float y2 = (v[4*p+2]-m)*rs*gv.z + bv.z;
    float y3 = (v[4*p+3]-m)*rs*gv.w + bv.w;
    if (xout) { float4 o = {y0,y1,y2,y3}; *(float4*)(xout + row*DM + d) = o; }
    if (xh) {
      h16x4 hv; hv[0]=(h16)(y0*16.f); hv[1]=(h16)(y1*16.f);
      hv[2]=(h16)(y2*16.f); hv[3]=(h16)(y3*16.f);
      *(h16x4*)(xh + row*DM + d) = hv;
    }
    if (dout) { float4 o = {y0,y1,y2,y3}; *(float4*)(dout + row*DM + d) = o; }
  }
}

// ---------------------------------------------------------------------------
// threefry2x32 (key=[0,42]) -> gumbel -> argmax. VERIFIED round 5 — DO NOT TOUCH.
// partitionable bits = b1 ^ b2, counter = (0, i).
// ---------------------------------------------------------------------------
__device__ __forceinline__ void threefry(u32 x0, u32 x1, u32& y0, u32& y1) {
  const u32 ks0 = 0u, ks1 = 42u, ks2 = 0x1BD11BDAu ^ 42u;
  x0 += ks0; x1 += ks1;
  #define TF_R(r) { x0 += x1; x1 = (x1 << r) | (x1 >> (32 - r)); x1 ^= x0; }
  TF_R(13) TF_R(15) TF_R(26) TF_R(6)  x0 += ks1; x1 += ks2 + 1u;
  TF_R(17) TF_R(29) TF_R(16) TF_R(24) x0 += ks2; x1 += ks0 + 2u;
  TF_R(13) TF_R(15) TF_R(26) TF_R(6)  x0 += ks0; x1 += ks1 + 3u;
  TF_R(17) TF_R(29) TF_R(16) TF_R(24) x0 += ks1; x1 += ks2 + 4u;
  TF_R(13) TF_R(15) TF_R(26) TF_R(6)  x0 += ks2; x1 += ks0 + 5u;
  #undef TF_R
  y0 = x0; y1 = x1;
}

__device__ __forceinline__ float gumbel_from(u32 bits) {
  float f = __uint_as_float((bits >> 9) | 0x3F800000u) - 1.0f;
  float u = (f > 0.0f) ? f : 1.17549435e-38f;
  float nl = (float)(-log((double)u));
  return -(float)log((double)nl);
}

__global__ __launch_bounds__(256) void k_gate(
    const float* __restrict__ x, const float* __restrict__ gw,
    const float* __restrict__ gb, int* __restrict__ chosen, int* __restrict__ counts)
{
  int wave = threadIdx.x >> 6, lane = threadIdx.x & 63;
  long t = (long)blockIdx.x*4 + wave;
  const float* xr = x + t*DM;
  float p[4] = {0.f,0.f,0.f,0.f};
  #pragma unroll
  for (int pp = 0; pp < 4; ++pp) {
    int d = pp*256 + lane*4;
    float4 xv = *(const float4*)(xr + d);
    #pragma unroll
    for (int e = 0; e < 4; ++e) {
      float4 gv = *(const float4*)(gw + e*DM + d);
      p[e] += xv.x*gv.x + xv.y*gv.y + xv.z*gv.z + xv.w*gv.w;
    }
  }
  #pragma unroll
  for (int e = 0; e < 4; ++e) p[e] = wave_sum(p[e]);
  if (lane == 0) {
    float best = -3.0e38f; int arg = 0;
    #pragma unroll
    for (int e = 0; e < 4; ++e) {
      float logit = p[e] + gb[e];
      u32 j = (u32)(4*t + e);
      u32 y0, y1;
      threefry(0u, j, y0, y1);
      float v = gumbel_from(y0 ^ y1) + logit;
      if (v > best) { best = v; arg = e; }
    }
    chosen[(int)t] = arg;
    atomicAdd(&counts[arg], 1);
  }
}

__global__ void k_offsets(const int* __restrict__ counts, int* __restrict__ eoff) {
  if (threadIdx.x == 0 && blockIdx.x == 0) {
    int o = 0;
    for (int e = 0; e < 4; ++e) { eoff[e] = o; o += (counts[e] + 127) & ~127; }
  }
}

__global__ void k_fill(int* __restrict__ p, int n) {
  int i = blockIdx.x*256 + threadIdx.x;
  if (i < n) p[i] = -1;
}

__global__ void k_scatter(const int* __restrict__ chosen, const int* __restrict__ eoff,
                          int* __restrict__ cursor, int* __restrict__ plist) {
  int t = blockIdx.x*256 + threadIdx.x;
  if (t >= BS) return;
  int e = chosen[t];
  int slot = atomicAdd(&cursor[e], 1);
  plist[eoff[e] + slot] = t;
}

// MoE layer 1 (gathered rows, 128x64 core): h = relu(x.w1[e]^T + b1[e])
__global__ __launch_bounds__(256) void k_e1(
    const h16* __restrict__ Xh, const h16* __restrict__ W1, const float* __restrict__ b1,
    const int* __restrict__ plist, const int* __restrict__ eoff, h16* __restrict__ Hh)
{
  __shared__ h16 lds[(128 + 64)*LDK];
  const int n0 = blockIdx.x*64, m0 = blockIdx.y*128;
  const int e = (m0 >= eoff[1]) + (m0 >= eoff[2]) + (m0 >= eoff[3]);
  f32x4 acc[4][2] = {};
  hgemm128_core<true>(Xh, W1 + (long)e*DFE*DM, 1024, 1024, 1024, m0, n0, plist, acc, lds);
  EPI_W;
  #pragma unroll
  for (int i = 0; i < 4; ++i)
    #pragma unroll
    for (int j = 0; j < 2; ++j)
      #pragma unroll
      for (int r = 0; r < 4; ++r) {
        int row = m0 + wr + i*16 + rb + r;
        int col = n0 + wc + j*16 + fr;
        float c = acc[i][j][r] * (1.0f/1024.0f) + b1[e*DFE + col];
        c = fmaxf(c, 0.0f);
        Hh[(long)row*DFE + col] = (h16)(c * 16.0f);
      }
}

// MoE layer 2 (bucket rows, 128x64 core, scatter out): y[t] = h.w2[e]^T + b2[e]
__global__ __launch_bounds__(256) void k_e2(
    const h16* __restrict__ Hh, const h16* __restrict__ W2, const float* __restrict__ b2,
    const int* __restrict__ plist, const int* __restrict__ eoff, float* __restrict__ y)
{
  __shared__ h16 lds[(128 + 64)*LDK];
  const int n0 = blockIdx.x*64, m0 = blockIdx.y*128;
  const int e = (m0 >= eoff[1]) + (m0 >= eoff[2]) + (m0 >= eoff[3]);
  f32x4 acc[4][2] = {};
  hgemm128_core<false>(Hh, W2 + (long)e*DM*DFE, 1024, DFE, DFE, m0, n0, nullptr, acc, lds);
  EPI_W;
  #pragma unroll
  for (int i = 0; i < 4; ++i)
    #pragma unroll
    for (int j = 0; j < 2; ++j)
      #pragma unroll
      for (int r = 0; r < 4; ++r) {
        int row = m0 + wr + i*16 + rb + r;
        int col = n0 + wc + j*16 + fr;
        int t = plist[row];
        if (t >= 0)
          y[(long)t*DM + col] = acc[i][j][r] * (1.0f/1024.0f) + b2[e*DM + col];
      }
}

// ---------------------------------------------------------------------------
extern "C" void kernel_launch(void* const* d_in, const int* in_sizes, int n_in,
                              void* d_out, int out_size, void* d_ws, size_t ws_size,
                              hipStream_t stream) {
  const float* src = (const float*)d_in[0];
  const float* pos = (const float*)d_in[1];
  const float* w3  = (const float*)d_in[2];
  const float* b3  = (const float*)d_in[3];
  const float* wo  = (const float*)d_in[4];
  const float* bo  = (const float*)d_in[5];
  const float* gw  = (const float*)d_in[6];
  const float* gb  = (const float*)d_in[7];
  const float* w1  = (const float*)d_in[8];
  const float* b1  = (const float*)d_in[9];
  const float* w2  = (const float*)d_in[10];
  const float* b2  = (const float*)d_in[11];
  const float* g1  = (const float*)d_in[12];
  const float* be1 = (const float*)d_in[13];
  const float* g2  = (const float*)d_in[14];
  const float* be2 = (const float*)d_in[15];
  float* out = (float*)d_out;
  char* ws = (char*)d_ws;
  if (ws_size < WS_NEEDED) return;

  auto H = [&](size_t off) { return (h16*)(ws + off); };
  auto F = [&](size_t off) { return (float*)(ws + off); };
  auto I = [&](size_t off) { return (int*)(ws + off); };

  // zero atomic counters (counts[4] + cursor[4] contiguous)
  k_zero8<<<1, 64, 0, stream>>>(I(OFF_COUNTS));

  // input + weight splits
  k_split_in<<<BS*DM/4/256, 256, 0, stream>>>(src, pos,
      H(OFF_QKH), H(OFF_QKL), H(OFF_SRCH), H(OFF_SRCL));
  k_split2<<<3*DM*DM/4/256, 256, 0, stream>>>(w3, H(OFF_W3H), H(OFF_W3L), 64.0f, 3*DM*DM/4);
  k_split2<<<DM*DM/4/256, 256, 0, stream>>>(wo, H(OFF_WOH), H(OFF_WOL), 64.0f, DM*DM/4);

  // QKV projection
  k_qkv<<<dim3(48, 64), 256, 0, stream>>>(
      H(OFF_QKH), H(OFF_QKL), H(OFF_SRCH), H(OFF_SRCL), H(OFF_W3H), H(OFF_W3L), b3,
      H(OFF_QH), H(OFF_QL), H(OFF_KH), H(OFF_KL), H(OFF_VH), H(OFF_VL));

  // fused flash attention (one dispatch, XCD-swizzled)
  k_attn<<<dim3(NCHUNK*NBH), 256, 0, stream>>>(
      H(OFF_QH), H(OFF_QL), H(OFF_KH), H(OFF_KL), H(OFF_VH), H(OFF_VL),
      H(OFF_OH), H(OFF_OL));

  // out projection + LN1
  k_out<<<dim3(16, 64), 256, 0, stream>>>(
      H(OFF_OH), H(OFF_OL), H(OFF_WOH), H(OFF_WOL), bo, F(OFF_ATT));
  k_ln<<<BS/4, 256, 0, stream>>>(src, F(OFF_ATT), g1, be1, F(OFF_X), H(OFF_XH), nullptr);

  // gate + expert bucketing (buckets padded to 128 rows)
  k_gate<<<BS/4, 256, 0, stream>>>(F(OFF_X), gw, gb, I(OFF_CHOSEN), I(OFF_COUNTS));
  k_offsets<<<1, 64, 0, stream>>>(I(OFF_COUNTS), I(OFF_EOFF));
  k_fill<<<(NPOS+255)/256, 256, 0, stream>>>(I(OFF_PLIST), NPOS);
  k_scatter<<<BS/256, 256, 0, stream>>>(I(OFF_CHOSEN), I(OFF_EOFF), I(OFF_CURSOR), I(OFF_PLIST));

  // MoE weights to f16 and bucketed expert FFN (128x64 core)
  k_tof16<<<NE*DFE*DM/4/256, 256, 0, stream>>>(w1, H(OFF_W1H), 64.0f, NE*DFE*DM/4);
  k_tof16<<<NE*DM*DFE/4/256, 256, 0, stream>>>(w2, H(OFF_W2H), 64.0f, NE*DM*DFE/4);
  k_e1<<<dim3(16, NPOS/128), 256, 0, stream>>>(
      H(OFF_XH), H(OFF_W1H), b1, I(OFF_PLIST), I(OFF_EOFF), H(OFF_HH));
  k_e2<<<dim3(16, NPOS/128), 256, 0, stream>>>(
      H(OFF_HH), H(OFF_W2H), b2, I(OFF_PLIST), I(OFF_EOFF), F(OFF_Y));

  // final LN2 -> output
  k_ln<<<BS/4, 256, 0, stream>>>(F(OFF_X), F(OFF_Y), g2, be2, nullptr, nullptr, out);
}

// Round 14
// 844.196 us; speedup vs baseline: 1.0172x; 1.0172x over previous
//
#include <hip/hip_runtime.h>
#include <cstdint>
#include <cstddef>

// ---------------------------------------------------------------------------
// TransformerEncoderLayer on MI355X (gfx950).
// Pre-gate GEMMs: f16 hi/lo split MFMA (3 mfma/product) — validated bit-equal
// to fp32 routing. QKV/out_proj: 128x128 tile (wave=64x64, 48 MFMA : 16
// ds_read per K-step -> MFMA-bound inner loop), double-buffered
// global_load_lds pipeline + XOR source swizzle (0 bank conflicts), and
// XCD-chunked 1D grid (contiguous m0-panels per XCD for L2 A-reuse).
// Attention: fused flash, swapped QK^T + in-register softmax + reg->reg P.
// Gate RNG: partitionable threefry, b1^b2 (VERIFIED round 5 — DO NOT TOUCH).
// MoE: bucketed per-expert f16 MFMA (128x64 core).
// ---------------------------------------------------------------------------

typedef _Float16 h16;
typedef h16 h16x8 __attribute__((ext_vector_type(8)));
typedef h16 h16x4 __attribute__((ext_vector_type(4)));
typedef __fp16 fp16x2 __attribute__((ext_vector_type(2)));   // cvt_pkrtz native type
typedef float f32x4 __attribute__((ext_vector_type(4)));
typedef uint32_t u32;

#define DM 1024
#define NH 16
#define HD 64
#define SEQ 1024
#define BB 8
#define BS (BB*SEQ)      /* 8192 tokens */
#define NBH (BB*NH)      /* 128 (b,h) pairs */
#define NE 4
#define DFE 1024
#define QB 64            /* query rows per attention chunk */
#define NCHUNK (SEQ/QB)  /* 16 */
#define LDK 40           /* LDS stride (h16) for MoE core slabs */
#define SLDA 32          /* linear LDS stride (h16) for gload_lds slabs */
#define FLD 72           /* LDS stride for 64-wide flash tiles (64+8 pad) */
#define NPOS (68*128)    /* 8704: bucket capacity, 128-padded per expert */

#define MFMA16(a,b,c) __builtin_amdgcn_mfma_f32_16x16x32_f16(a,b,c,0,0,0)

// ---- workspace layout (bytes). E = one h16 plane of [8192][1024]. ----
static constexpr size_t E = (size_t)BS*DM*2;            // 16,777,216
static constexpr size_t OFF_QKH = 0;                    // qk split (dead after qkv)
static constexpr size_t OFF_QKL = E;
static constexpr size_t OFF_SRCH= 2*E;
static constexpr size_t OFF_SRCL= 3*E;
static constexpr size_t OFF_W3H = 4*E;
static constexpr size_t OFF_W3L = 4*E + (size_t)3*DM*DM*2;
static constexpr size_t OFF_WOH = 4*E + (size_t)6*DM*DM*2;
static constexpr size_t OFF_WOL = 4*E + (size_t)7*DM*DM*2;   // ends at 5E
static constexpr size_t OFF_QH  = 5*E;                  // Q,K [bh][s][d]; V^T [bh][d][s]
static constexpr size_t OFF_QL  = 6*E;
static constexpr size_t OFF_KH  = 7*E;
static constexpr size_t OFF_KL  = 8*E;
static constexpr size_t OFF_VH  = 9*E;
static constexpr size_t OFF_VL  = 10*E;
static constexpr size_t OFF_OH  = 0;                    // after flash (qk dead)
static constexpr size_t OFF_OL  = E;
static constexpr size_t OFF_ATT = 2*E;                  // fp32 (src splits dead)
static constexpr size_t OFF_X   = 5*E;                  // fp32 2E (Q,Ql dead)
static constexpr size_t OFF_XH  = 7*E;                  // f16 x*16 (Kh dead)
static constexpr size_t OFF_W1H = 8*E;                  // f16 (Kl dead)
static constexpr size_t OFF_W2H = 8*E + (size_t)NE*DFE*DM*2;  // ends at 9E
static constexpr size_t OFF_HH  = 9*E;                  // bucket h f16 [NPOS][1024] (V dead)
static constexpr size_t OFF_Y   = 11*E;                 // fp32 2E
static constexpr size_t OFF_CHOSEN = 13*E;
static constexpr size_t OFF_COUNTS = 13*E + 32768;
static constexpr size_t OFF_CURSOR = OFF_COUNTS + 16;
static constexpr size_t OFF_EOFF   = OFF_CURSOR + 16;
static constexpr size_t OFF_PLIST  = OFF_EOFF + 16;
static constexpr size_t WS_NEEDED  = OFF_PLIST + (size_t)NPOS*4;

// ---------------------------------------------------------------------------
__device__ __forceinline__ void store_split(h16* H, h16* L, size_t idx, float v) {
  h16 h = (h16)v;
  H[idx] = h;
  L[idx] = (h16)((v - (float)h) * 4096.0f);
}

__device__ __forceinline__ float wave_sum(float v) {
  #pragma unroll
  for (int o = 32; o; o >>= 1) v += __shfl_xor(v, o);
  return v;
}

// pack two floats to f16x2 (RTZ) and return the u32 word + the two f16 values
__device__ __forceinline__ u32 pk2(float a, float b, float& fa, float& fb) {
  union { fp16x2 h; u32 w; } u;
  u.h = __builtin_amdgcn_cvt_pkrtz(a, b);
  fa = (float)u.h[0];
  fb = (float)u.h[1];
  return u.w;
}
__device__ __forceinline__ u32 pk2w(float a, float b) {
  union { fp16x2 h; u32 w; } u;
  u.h = __builtin_amdgcn_cvt_pkrtz(a, b);
  return u.w;
}

// async global->LDS, 16B per lane; LDS dest = uniform base + lane*16
__device__ __forceinline__ void gload16(const void* g, void* l) {
  __builtin_amdgcn_global_load_lds(
      (const __attribute__((address_space(1))) u32*)g,
      (__attribute__((address_space(3))) u32*)l, 16, 0, 0);
}

// ---------------------------------------------------------------------------
// 128(M)x128(N) split-f16 MFMA core: 4 waves 2x2 (each 64x64 = 4x4 frags),
// double-buffered global_load_lds staging, XOR source swizzle.
// Per wave per K-step: 48 MFMA (~240cyc) vs 16 ds_read_b128 (~192cyc)
// -> MFMA-bound inner loop. LDS 64KB (2 blocks/CU).
// ---------------------------------------------------------------------------
__device__ __forceinline__ void gemm128x128_core(
    const h16* __restrict__ Ah, const h16* __restrict__ Al,
    const h16* __restrict__ Bh, const h16* __restrict__ Bl,
    int K, int lda, int ldb, int m0, int n0,
    f32x4 (&a1)[4][4], f32x4 (&a2)[4][4], h16* lds)
{
  constexpr int BUF = 4*128*SLDA;   // 16384 h16 = 32KB per buffer
  const int tid = threadIdx.x, lane = tid & 63, wid = tid >> 6;
  const int wr = (wid >> 1) * 64, wc = (wid & 1) * 64;
  const int lr16 = lane >> 2, lgrp = lane & 3;
  const int rA = wid*32 + lr16;               // A rows: +0 and +16
  const int rB = wid*32 + lr16;               // B rows: +0 and +16
  const int swA = (rA >> 1) & 3;              // row bits 1..2 (same for +16)
  const int swB = (rB >> 1) & 3;
  const long gA0 = (long)(m0 + rA)      * lda + ((lgrp ^ swA) << 3);
  const long gA1 = (long)(m0 + rA + 16) * lda + ((lgrp ^ swA) << 3);
  const long gB0 = (long)(n0 + rB)      * ldb + ((lgrp ^ swB) << 3);
  const long gB1 = (long)(n0 + rB + 16) * ldb + ((lgrp ^ swB) << 3);
  const int oR0 = (wid*32)*SLDA, oR1 = (wid*32+16)*SLDA;
  const int fr = lane & 15, gi = lane >> 4;
  const int pcol = ((gi ^ ((lane >> 1) & 3)) << 3);
  const int nt = K >> 5;

  auto stage = [&](int t, int buf) {
    h16* base = lds + buf*BUF;
    h16* sAh = base;                h16* sAl = base + 128*SLDA;
    h16* sBh = base + 2*128*SLDA;   h16* sBl = base + 3*128*SLDA;
    const int k0 = t << 5;
    gload16(Ah + gA0 + k0, sAh + oR0);
    gload16(Ah + gA1 + k0, sAh + oR1);
    gload16(Al + gA0 + k0, sAl + oR0);
    gload16(Al + gA1 + k0, sAl + oR1);
    gload16(Bh + gB0 + k0, sBh + oR0);
    gload16(Bh + gB1 + k0, sBh + oR1);
    gload16(Bl + gB0 + k0, sBl + oR0);
    gload16(Bl + gB1 + k0, sBl + oR1);
  };

  stage(0, 0);
  __syncthreads();                       // tile 0 resident
  int cur = 0;
  for (int t = 0; t < nt; ++t) {
    if (t + 1 < nt) stage(t + 1, cur ^ 1);   // issue-early: hides under MFMA
    h16* base = lds + cur*BUF;
    h16* sAh = base;                h16* sAl = base + 128*SLDA;
    h16* sBh = base + 2*128*SLDA;   h16* sBl = base + 3*128*SLDA;
    h16x8 ah[4], al[4], bh[4], bl[4];
    #pragma unroll
    for (int i = 0; i < 4; ++i) {
      ah[i] = *(const h16x8*)(sAh + (wr + i*16 + fr)*SLDA + pcol);
      al[i] = *(const h16x8*)(sAl + (wr + i*16 + fr)*SLDA + pcol);
    }
    #pragma unroll
    for (int j = 0; j < 4; ++j) {
      bh[j] = *(const h16x8*)(sBh + (wc + j*16 + fr)*SLDA + pcol);
      bl[j] = *(const h16x8*)(sBl + (wc + j*16 + fr)*SLDA + pcol);
    }
    #pragma unroll
    for (int i = 0; i < 4; ++i)
      #pragma unroll
      for (int j = 0; j < 4; ++j) {
        a1[i][j] = MFMA16(ah[i], bh[j], a1[i][j]);
        a2[i][j] = MFMA16(ah[i], bl[j], a2[i][j]);
        a2[i][j] = MFMA16(al[i], bh[j], a2[i][j]);
      }
    __syncthreads();                     // drains t+1 loads + all reads of buf
    cur ^= 1;
  }
}

#define EPI_X \
  const int lane = threadIdx.x & 63, wid = threadIdx.x >> 6; \
  const int wr = (wid>>1)*64, wc = (wid&1)*64; \
  const int fr = lane & 15, rb = (lane>>4)*4;

#define EPI_W \
  const int lane = threadIdx.x & 63, wid = threadIdx.x >> 6; \
  const int wr = (wid>>1)*64, wc = (wid&1)*32; \
  const int fr = lane & 15, rb = (lane>>4)*4;

// ---------------------------------------------------------------------------
// 128(M)x64(N) f16 single MFMA core for MoE (unchanged, validated).
// ---------------------------------------------------------------------------
template<bool GATHER>
__device__ __forceinline__ void hgemm128_core(
    const h16* __restrict__ A, const h16* __restrict__ B,
    int K, int lda, int ldb, int m0, int n0, const int* __restrict__ rowmap,
    f32x4 (&acc)[4][2], h16* lds)
{
  const int tid = threadIdx.x, lane = tid & 63, wid = tid >> 6;
  const int wr = (wid >> 1) * 64, wc = (wid & 1) * 32;
  h16* sA = lds;              // [128][LDK]
  h16* sB = lds + 128*LDK;    // [64][LDK]
  const int arow = tid >> 1, akc = (tid & 1) * 16;
  const int brow = tid >> 2, bkc = (tid & 3) * 8;
  long abase; bool aval = true;
  if (GATHER) { int t = rowmap[m0 + arow]; aval = (t >= 0);
                abase = (long)(aval ? t : 0) * lda + akc; }
  else          abase = (long)(m0 + arow) * lda + akc;
  const long bbase = (long)(n0 + brow) * ldb + bkc;
  const int fr = lane & 15, kg = (lane >> 4) << 3;
  for (int k0 = 0; k0 < K; k0 += 32) {
    __syncthreads();
    uint4 va0 = (!GATHER || aval) ? *(const uint4*)(A + abase + k0)     : make_uint4(0,0,0,0);
    uint4 va1 = (!GATHER || aval) ? *(const uint4*)(A + abase + k0 + 8) : make_uint4(0,0,0,0);
    *(uint4*)(sA + arow*LDK + akc)     = va0;
    *(uint4*)(sA + arow*LDK + akc + 8) = va1;
    *(uint4*)(sB + brow*LDK + bkc)     = *(const uint4*)(B + bbase + k0);
    __syncthreads();
    h16x8 a_[4], b_[2];
    #pragma unroll
    for (int i = 0; i < 4; ++i)
      a_[i] = *(const h16x8*)(sA + (wr + i*16 + fr)*LDK + kg);
    #pragma unroll
    for (int j = 0; j < 2; ++j)
      b_[j] = *(const h16x8*)(sB + (wc + j*16 + fr)*LDK + kg);
    #pragma unroll
    for (int i = 0; i < 4; ++i)
      #pragma unroll
      for (int j = 0; j < 2; ++j)
        acc[i][j] = MFMA16(a_[i], b_[j], acc[i][j]);
  }
}

// ---------------------------------------------------------------------------
// prep kernels
// ---------------------------------------------------------------------------
__global__ void k_zero8(int* __restrict__ p) {
  if (threadIdx.x < 8) p[threadIdx.x] = 0;   // counts[4] + cursor[4]
}

__global__ void k_split_in(const float* __restrict__ src, const float* __restrict__ pos,
                           h16* __restrict__ qkH, h16* __restrict__ qkL,
                           h16* __restrict__ sH,  h16* __restrict__ sL) {
  int i = blockIdx.x*256 + threadIdx.x;
  float4 s = ((const float4*)src)[i];
  float4 p = ((const float4*)pos)[i];
  float sv[4] = {s.x, s.y, s.z, s.w};
  float qv[4] = {s.x+p.x, s.y+p.y, s.z+p.z, s.w+p.w};
  h16x4 sh, sl, qh, ql;
  #pragma unroll
  for (int q = 0; q < 4; ++q) {
    float xs = sv[q] * 16.0f; h16 hs = (h16)xs;
    sh[q] = hs; sl[q] = (h16)((xs - (float)hs) * 4096.0f);
    float xq = qv[q] * 16.0f; h16 hq = (h16)xq;
    qh[q] = hq; ql[q] = (h16)((xq - (float)hq) * 4096.0f);
  }
  ((h16x4*)sH)[i] = sh; ((h16x4*)sL)[i] = sl;
  ((h16x4*)qkH)[i] = qh; ((h16x4*)qkL)[i] = ql;
}

__global__ void k_split2(const float* __restrict__ a,
                         h16* __restrict__ H, h16* __restrict__ L, float scale, int n4) {
  int i = blockIdx.x*256 + threadIdx.x;
  if (i >= n4) return;
  float4 v = ((const float4*)a)[i];
  float vv[4] = {v.x, v.y, v.z, v.w};
  h16x4 hv, lv;
  #pragma unroll
  for (int q = 0; q < 4; ++q) {
    float x = vv[q] * scale;
    h16 h = (h16)x;
    hv[q] = h;
    lv[q] = (h16)((x - (float)h) * 4096.0f);
  }
  ((h16x4*)H)[i] = hv;
  ((h16x4*)L)[i] = lv;
}

__global__ void k_tof16(const float* __restrict__ a, h16* __restrict__ H, float scale, int n4) {
  int i = blockIdx.x*256 + threadIdx.x;
  if (i >= n4) return;
  float4 v = ((const float4*)a)[i];
  h16x4 hv;
  hv[0] = (h16)(v.x*scale); hv[1] = (h16)(v.y*scale);
  hv[2] = (h16)(v.z*scale); hv[3] = (h16)(v.w*scale);
  ((h16x4*)H)[i] = hv;
}

// ---------------------------------------------------------------------------
// QKV projection (128x128 split MFMA, XCD-chunked 1D grid: 1536 = 8 XCD x
// (8 m0-panels x 24 n0) — A-panel L2-resident across 24 consecutive blocks)
// ---------------------------------------------------------------------------
__global__ __launch_bounds__(256) void k_qkv(
    const h16* __restrict__ qkh, const h16* __restrict__ qkl,
    const h16* __restrict__ sh,  const h16* __restrict__ sl,
    const h16* __restrict__ Wh,  const h16* __restrict__ Wl, const float* __restrict__ bias,
    h16* __restrict__ Qh, h16* __restrict__ Ql, h16* __restrict__ Kh, h16* __restrict__ Kl,
    h16* __restrict__ Vh, h16* __restrict__ Vl)
{
  __shared__ h16 lds[2*4*128*SLDA];   // 65,536 B (double buffer)
  const int bid = blockIdx.x;                       // 0..1535
  const int swz = (bid & 7) * 192 + (bid >> 3);     // bijective (1536 = 8*192)
  const int m0 = (swz / 24) * 128;
  const int n0 = (swz % 24) * 128;
  const bool isV = (n0 >= 2048);
  f32x4 a1[4][4] = {}; f32x4 a2[4][4] = {};
  gemm128x128_core(isV ? sh : qkh, isV ? sl : qkl, Wh, Wl,
                   1024, 1024, 1024, m0, n0, a1, a2, lds);
  EPI_X;
  #pragma unroll
  for (int i = 0; i < 4; ++i)
    #pragma unroll
    for (int j = 0; j < 4; ++j)
      #pragma unroll
      for (int r = 0; r < 4; ++r) {
        int row = m0 + wr + i*16 + rb + r;
        int col = n0 + wc + j*16 + fr;
        float c = (a1[i][j][r] + a2[i][j][r]*(1.0f/4096.0f)) * (1.0f/1024.0f) + bias[col];
        int b = row >> 10, s = row & 1023;
        int cc = col & 1023, h = cc >> 6, d = cc & 63;
        long bh = (long)b*NH + h;
        float cs = c * 16.0f;
        if (col < 1024)      store_split(Qh, Ql, (bh*SEQ + s)*HD + d, cs);
        else if (col < 2048) store_split(Kh, Kl, (bh*SEQ + s)*HD + d, cs);
        else                 store_split(Vh, Vl, (bh*HD + d)*SEQ + s, cs);
      }
}

// ---------------------------------------------------------------------------
// Fused flash attention (round 12, verified): swapped QK^T, in-reg softmax,
// reg->reg P via cvt_pkrtz + shfl.
// ---------------------------------------------------------------------------
__global__ __launch_bounds__(256) void k_attn(
    const h16* __restrict__ Qh, const h16* __restrict__ Ql,
    const h16* __restrict__ Kh, const h16* __restrict__ Kl,
    const h16* __restrict__ Vh, const h16* __restrict__ Vl,
    h16* __restrict__ Oh, h16* __restrict__ Ol)
{
  __shared__ h16 lds[4*64*FLD];   // 36,864 B (K h/l + V h/l)
  h16* sKh = lds;            h16* sKl = lds + 64*FLD;
  h16* sVh = lds + 2*64*FLD; h16* sVl = lds + 3*64*FLD;
  const int bid = blockIdx.x;                  // 0..2047
  const int swz = (bid & 7) * 256 + (bid >> 3);
  const int bh = swz >> 4;
  const int q0 = (swz & 15) * QB;
  const int tid = threadIdx.x, lane = tid & 63, w = tid >> 6;
  const int fr = lane & 15, hg = lane >> 4;   // 0..3
  const int kg = hg << 3;
  const long qbase = ((long)bh*SEQ + q0 + w*16 + fr) * HD;
  h16x8 qh[2], ql[2];
  qh[0] = *(const h16x8*)(Qh + qbase + kg);
  qh[1] = *(const h16x8*)(Qh + qbase + 32 + kg);
  ql[0] = *(const h16x8*)(Ql + qbase + kg);
  ql[1] = *(const h16x8*)(Ql + qbase + 32 + kg);
  f32x4 o1[4] = {}, o2[4] = {};      // O[q=4hg+r][d=16jd+fr]
  float mrow = -3.0e38f, lrow = 0.f; // for q-row = w*16 + fr
  const int srow = tid >> 2, skc = (tid & 3) << 4;
  const long kbase = ((long)bh*SEQ + srow) * HD + skc;
  const long vbase = ((long)bh*HD + srow) * SEQ + skc;
  const int srcA = fr + ((hg & 1) << 5);
  const int srcB = srcA + 16;
  for (int kt = 0; kt < NCHUNK; ++kt) {
    const int n0 = kt * QB;
    __syncthreads();
    {
      const long ka = kbase + (long)n0*HD;
      *(uint4*)(sKh + srow*FLD + skc)     = *(const uint4*)(Kh + ka);
      *(uint4*)(sKh + srow*FLD + skc + 8) = *(const uint4*)(Kh + ka + 8);
      *(uint4*)(sKl + srow*FLD + skc)     = *(const uint4*)(Kl + ka);
      *(uint4*)(sKl + srow*FLD + skc + 8) = *(const uint4*)(Kl + ka + 8);
      const long va = vbase + n0;
      *(uint4*)(sVh + srow*FLD + skc)     = *(const uint4*)(Vh + va);
      *(uint4*)(sVh + srow*FLD + skc + 8) = *(const uint4*)(Vh + va + 8);
      *(uint4*)(sVl + srow*FLD + skc)     = *(const uint4*)(Vl + va);
      *(uint4*)(sVl + srow*FLD + skc + 8) = *(const uint4*)(Vl + va + 8);
    }
    __syncthreads();
    f32x4 s1[4] = {}, s2[4] = {};
    #pragma unroll
    for (int ks = 0; ks < 2; ++ks)
      #pragma unroll
      for (int j = 0; j < 4; ++j) {
        h16x8 kh = *(const h16x8*)(sKh + (j*16 + fr)*FLD + ks*32 + kg);
        h16x8 kl = *(const h16x8*)(sKl + (j*16 + fr)*FLD + ks*32 + kg);
        s1[j] = MFMA16(kh, qh[ks], s1[j]);
        s2[j] = MFMA16(kh, ql[ks], s2[j]);
        s2[j] = MFMA16(kl, qh[ks], s2[j]);
      }
    float p[4][4];
    float tmax = -3.0e38f;
    #pragma unroll
    for (int j = 0; j < 4; ++j)
      #pragma unroll
      for (int r = 0; r < 4; ++r) {
        float sc = (s1[j][r] + s2[j][r]*(1.0f/4096.0f)) * (0.125f/256.0f);
        p[j][r] = sc;
        tmax = fmaxf(tmax, sc);
      }
    tmax = fmaxf(tmax, __shfl_xor(tmax, 16));
    tmax = fmaxf(tmax, __shfl_xor(tmax, 32));
    float mn = fmaxf(mrow, tmax);
    float sclf = __expf(mrow - mn);
    mrow = mn;
    float psum = 0.f;
    #pragma unroll
    for (int j = 0; j < 4; ++j)
      #pragma unroll
      for (int r = 0; r < 4; ++r) { float e = __expf(p[j][r] - mn); p[j][r] = e; psum += e; }
    psum += __shfl_xor(psum, 16);
    psum += __shfl_xor(psum, 32);
    lrow = lrow*sclf + psum;
    #pragma unroll
    for (int r = 0; r < 4; ++r) {
      float sq = __shfl(sclf, hg*4 + r);
      #pragma unroll
      for (int jd = 0; jd < 4; ++jd) { o1[jd][r] *= sq; o2[jd][r] *= sq; }
    }
    u32 hp[4][2], lp[4][2];
    #pragma unroll
    for (int j = 0; j < 4; ++j)
      #pragma unroll
      for (int rp = 0; rp < 2; ++rp) {
        float a = p[j][2*rp]   * 512.0f;
        float b = p[j][2*rp+1] * 512.0f;
        float fa, fb;
        hp[j][rp] = pk2(a, b, fa, fb);
        lp[j][rp] = pk2w((a - fa) * 4096.0f, (b - fb) * 4096.0f);
      }
    #pragma unroll
    for (int ks = 0; ks < 2; ++ks) {
      const int j0 = 2*ks, j1 = 2*ks + 1;
      u32 hA0 = (u32)__shfl((int)hp[j0][0], srcA), hA1 = (u32)__shfl((int)hp[j0][1], srcA);
      u32 hB0 = (u32)__shfl((int)hp[j0][0], srcB), hB1 = (u32)__shfl((int)hp[j0][1], srcB);
      u32 hC0 = (u32)__shfl((int)hp[j1][0], srcA), hC1 = (u32)__shfl((int)hp[j1][1], srcA);
      u32 hD0 = (u32)__shfl((int)hp[j1][0], srcB), hD1 = (u32)__shfl((int)hp[j1][1], srcB);
      u32 lA0 = (u32)__shfl((int)lp[j0][0], srcA), lA1 = (u32)__shfl((int)lp[j0][1], srcA);
      u32 lB0 = (u32)__shfl((int)lp[j0][0], srcB), lB1 = (u32)__shfl((int)lp[j0][1], srcB);
      u32 lC0 = (u32)__shfl((int)lp[j1][0], srcA), lC1 = (u32)__shfl((int)lp[j1][1], srcA);
      u32 lD0 = (u32)__shfl((int)lp[j1][0], srcB), lD1 = (u32)__shfl((int)lp[j1][1], srcB);
      const bool hij = (hg & 2) != 0;
      union { u32 w[4]; h16x8 v; } pa, pb;
      pa.w[0] = hij ? hC0 : hA0;  pa.w[1] = hij ? hC1 : hA1;
      pa.w[2] = hij ? hD0 : hB0;  pa.w[3] = hij ? hD1 : hB1;
      pb.w[0] = hij ? lC0 : lA0;  pb.w[1] = hij ? lC1 : lA1;
      pb.w[2] = hij ? lD0 : lB0;  pb.w[3] = hij ? lD1 : lB1;
      #pragma unroll
      for (int jd = 0; jd < 4; ++jd) {
        h16x8 vh = *(const h16x8*)(sVh + (jd*16 + fr)*FLD + ks*32 + kg);
        h16x8 vl = *(const h16x8*)(sVl + (jd*16 + fr)*FLD + ks*32 + kg);
        o1[jd] = MFMA16(pa.v, vh, o1[jd]);
        o2[jd] = MFMA16(pa.v, vl, o2[jd]);
        o2[jd] = MFMA16(pb.v, vh, o2[jd]);
      }
    }
  }
  float lq[4];
  #pragma unroll
  for (int r = 0; r < 4; ++r) lq[r] = __shfl(lrow, hg*4 + r);
  const int b = bh >> 4, h = bh & 15;
  #pragma unroll
  for (int jd = 0; jd < 4; ++jd)
    #pragma unroll
    for (int r = 0; r < 4; ++r) {
      int qrow = q0 + w*16 + hg*4 + r;
      int d = jd*16 + fr;
      float ov = (o1[jd][r] + o2[jd][r]*(1.0f/4096.0f)) / (512.0f*16.0f*lq[r]);
      store_split(Oh, Ol, ((long)b*SEQ + qrow)*DM + h*HD + d, ov*16.0f);
    }
}

// out_proj (128x128 split, XCD-chunked grid 512 = 8 x (8 m0 x 8 n0))
__global__ __launch_bounds__(256) void k_out(
    const h16* __restrict__ Oh, const h16* __restrict__ Ol,
    const h16* __restrict__ Wh, const h16* __restrict__ Wl,
    const float* __restrict__ bias, float* __restrict__ attn)
{
  __shared__ h16 lds[2*4*128*SLDA];
  const int bid = blockIdx.x;                       // 0..511
  const int swz = (bid & 7) * 64 + (bid >> 3);      // bijective (512 = 8*64)
  const int m0 = (swz / 8) * 128;
  const int n0 = (swz % 8) * 128;
  f32x4 a1[4][4] = {}; f32x4 a2[4][4] = {};
  gemm128x128_core(Oh, Ol, Wh, Wl, 1024, 1024, 1024, m0, n0, a1, a2, lds);
  EPI_X;
  #pragma unroll
  for (int i = 0; i < 4; ++i)
    #pragma unroll
    for (int j = 0; j < 4; ++j)
      #pragma unroll
      for (int r = 0; r < 4; ++r) {
        int row = m0 + wr + i*16 + rb + r;
        int col = n0 + wc + j*16 + fr;
        attn[(long)row*DM + col] =
            (a1[i][j][r] + a2[i][j][r]*(1.0f/4096.0f)) * (1.0f/1024.0f) + bias[col];
      }
}

// LayerNorm of (A + Badd): optional fp32 out, f16(x*16) out, direct out
__global__ __launch_bounds__(256) void k_ln(
    const float* __restrict__ A, const float* __restrict__ Badd,
    const float* __restrict__ g, const float* __restrict__ be,
    float* __restrict__ xout, h16* __restrict__ xh, float* __restrict__ dout)
{
  int wave = threadIdx.x >> 6, lane = threadIdx.x & 63;
  long row = (long)blockIdx.x*4 + wave;
  const float* ar = A + row*DM; const float* br = Badd + row*DM;
  float v[16]; float s = 0.0f;
  #pragma unroll
  for (int p = 0; p < 4; ++p) {
    int d = p*256 + lane*4;
    float4 a = *(const float4*)(ar + d);
    float4 b = *(const float4*)(br + d);
    float t0=a.x+b.x, t1=a.y+b.y, t2=a.z+b.z, t3=a.w+b.w;
    v[4*p+0]=t0; v[4*p+1]=t1; v[4*p+2]=t2; v[4*p+3]=t3;
    s += t0+t1+t2+t3;
  }
  s = wave_sum(s);
  float m = s * (1.0f/1024.0f);
  float q = 0.0f;
  #pragma unroll
  for (int i = 0; i < 16; ++i) { float dd = v[i]-m; q += dd*dd; }
  q = wave_sum(q);
  float rs = (float)(1.0 / sqrt((double)(q * (1.0f/1024.0f) + 1e-5f)));
  #pragma unroll
  for (int p = 0; p < 4; ++p) {
    int d = p*256 + lane*4;
    float4 gv = *(const float4*)(g + d);
    float4 bv = *(const float4*)(be + d);
    float y0 = (v[4*p+0]-m)*rs*gv.x + bv.x;
    float y1 = (v[4*p+1]-m)*rs*gv.y + bv.y;
    float y2 = (v[4*p+2]-m)*rs*gv.z + bv.z;
    float y3 = (v[4*p+3]-m)*rs*gv.w + bv.w;
    if (xout) { float4 o = {y0,y1,y2,y3}; *(float4*)(xout + row*DM + d) = o; }
    if (xh) {
      h16x4 hv; hv[0]=(h16)(y0*16.f); hv[1]=(h16)(y1*16.f);
      hv[2]=(h16)(y2*16.f); hv[3]=(h16)(y3*16.f);
      *(h16x4*)(xh + row*DM + d) = hv;
    }
    if (dout) { float4 o = {y0,y1,y2,y3}; *(float4*)(dout + row*DM + d) = o; }
  }
}

// ---------------------------------------------------------------------------
// threefry2x32 (key=[0,42]) -> gumbel -> argmax. VERIFIED round 5 — DO NOT TOUCH.
// partitionable bits = b1 ^ b2, counter = (0, i).
// ---------------------------------------------------------------------------
__device__ __forceinline__ void threefry(u32 x0, u32 x1, u32& y0, u32& y1) {
  const u32 ks0 = 0u, ks1 = 42u, ks2 = 0x1BD11BDAu ^ 42u;
  x0 += ks0; x1 += ks1;
  #define TF_R(r) { x0 += x1; x1 = (x1 << r) | (x1 >> (32 - r)); x1 ^= x0; }
  TF_R(13) TF_R(15) TF_R(26) TF_R(6)  x0 += ks1; x1 += ks2 + 1u;
  TF_R(17) TF_R(29) TF_R(16) TF_R(24) x0 += ks2; x1 += ks0 + 2u;
  TF_R(13) TF_R(15) TF_R(26) TF_R(6)  x0 += ks0; x1 += ks1 + 3u;
  TF_R(17) TF_R(29) TF_R(16) TF_R(24) x0 += ks1; x1 += ks2 + 4u;
  TF_R(13) TF_R(15) TF_R(26) TF_R(6)  x0 += ks2; x1 += ks0 + 5u;
  #undef TF_R
  y0 = x0; y1 = x1;
}

__device__ __forceinline__ float gumbel_from(u32 bits) {
  float f = __uint_as_float((bits >> 9) | 0x3F800000u) - 1.0f;
  float u = (f > 0.0f) ? f : 1.17549435e-38f;
  float nl = (float)(-log((double)u));
  return -(float)log((double)nl);
}

__global__ __launch_bounds__(256) void k_gate(
    const float* __restrict__ x, const float* __restrict__ gw,
    const float* __restrict__ gb, int* __restrict__ chosen, int* __restrict__ counts)
{
  int wave = threadIdx.x >> 6, lane = threadIdx.x & 63;
  long t = (long)blockIdx.x*4 + wave;
  const float* xr = x + t*DM;
  float p[4] = {0.f,0.f,0.f,0.f};
  #pragma unroll
  for (int pp = 0; pp < 4; ++pp) {
    int d = pp*256 + lane*4;
    float4 xv = *(const float4*)(xr + d);
    #pragma unroll
    for (int e = 0; e < 4; ++e) {
      float4 gv = *(const float4*)(gw + e*DM + d);
      p[e] += xv.x*gv.x + xv.y*gv.y + xv.z*gv.z + xv.w*gv.w;
    }
  }
  #pragma unroll
  for (int e = 0; e < 4; ++e) p[e] = wave_sum(p[e]);
  if (lane == 0) {
    float best = -3.0e38f; int arg = 0;
    #pragma unroll
    for (int e = 0; e < 4; ++e) {
      float logit = p[e] + gb[e];
      u32 j = (u32)(4*t + e);
      u32 y0, y1;
      threefry(0u, j, y0, y1);
      float v = gumbel_from(y0 ^ y1) + logit;
      if (v > best) { best = v; arg = e; }
    }
    chosen[(int)t] = arg;
    atomicAdd(&counts[arg], 1);
  }
}

__global__ void k_offsets(const int* __restrict__ counts, int* __restrict__ eoff) {
  if (threadIdx.x == 0 && blockIdx.x == 0) {
    int o = 0;
    for (int e = 0; e < 4; ++e) { eoff[e] = o; o += (counts[e] + 127) & ~127; }
  }
}

__global__ void k_fill(int* __restrict__ p, int n) {
  int i = blockIdx.x*256 + threadIdx.x;
  if (i < n) p[i] = -1;
}

__global__ void k_scatter(const int* __restrict__ chosen, const int* __restrict__ eoff,
                          int* __restrict__ cursor, int* __restrict__ plist) {
  int t = blockIdx.x*256 + threadIdx.x;
  if (t >= BS) return;
  int e = chosen[t];
  int slot = atomicAdd(&cursor[e], 1);
  plist[eoff[e] + slot] = t;
}

// MoE layer 1 (gathered rows, 128x64 core): h = relu(x.w1[e]^T + b1[e])
__global__ __launch_bounds__(256) void k_e1(
    const h16* __restrict__ Xh, const h16* __restrict__ W1, const float* __restrict__ b1,
    const int* __restrict__ plist, const int* __restrict__ eoff, h16* __restrict__ Hh)
{
  __shared__ h16 lds[(128 + 64)*LDK];
  const int n0 = blockIdx.x*64, m0 = blockIdx.y*128;
  const int e = (m0 >= eoff[1]) + (m0 >= eoff[2]) + (m0 >= eoff[3]);
  f32x4 acc[4][2] = {};
  hgemm128_core<true>(Xh, W1 + (long)e*DFE*DM, 1024, 1024, 1024, m0, n0, plist, acc, lds);
  EPI_W;
  #pragma unroll
  for (int i = 0; i < 4; ++i)
    #pragma unroll
    for (int j = 0; j < 2; ++j)
      #pragma unroll
      for (int r = 0; r < 4; ++r) {
        int row = m0 + wr + i*16 + rb + r;
        int col = n0 + wc + j*16 + fr;
        float c = acc[i][j][r] * (1.0f/1024.0f) + b1[e*DFE + col];
        c = fmaxf(c, 0.0f);
        Hh[(long)row*DFE + col] = (h16)(c * 16.0f);
      }
}

// MoE layer 2 (bucket rows, 128x64 core, scatter out): y[t] = h.w2[e]^T + b2[e]
__global__ __launch_bounds__(256) void k_e2(
    const h16* __restrict__ Hh, const h16* __restrict__ W2, const float* __restrict__ b2,
    const int* __restrict__ plist, const int* __restrict__ eoff, float* __restrict__ y)
{
  __shared__ h16 lds[(128 + 64)*LDK];
  const int n0 = blockIdx.x*64, m0 = blockIdx.y*128;
  const int e = (m0 >= eoff[1]) + (m0 >= eoff[2]) + (m0 >= eoff[3]);
  f32x4 acc[4][2] = {};
  hgemm128_core<false>(Hh, W2 + (long)e*DM*DFE, 1024, DFE, DFE, m0, n0, nullptr, acc, lds);
  EPI_W;
  #pragma unroll
  for (int i = 0; i < 4; ++i)
    #pragma unroll
    for (int j = 0; j < 2; ++j)
      #pragma unroll
      for (int r = 0; r < 4; ++r) {
        int row = m0 + wr + i*16 + rb + r;
        int col = n0 + wc + j*16 + fr;
        int t = plist[row];
        if (t >= 0)
          y[(long)t*DM + col] = acc[i][j][r] * (1.0f/1024.0f) + b2[e*DM + col];
      }
}

// ---------------------------------------------------------------------------
extern "C" void kernel_launch(void* const* d_in, const int* in_sizes, int n_in,
                              void* d_out, int out_size, void* d_ws, size_t ws_size,
                              hipStream_t stream) {
  const float* src = (const float*)d_in[0];
  const float* pos = (const float*)d_in[1];
  const float* w3  = (const float*)d_in[2];
  const float* b3  = (const float*)d_in[3];
  const float* wo  = (const float*)d_in[4];
  const float* bo  = (const float*)d_in[5];
  const float* gw  = (const float*)d_in[6];
  const float* gb  = (const float*)d_in[7];
  const float* w1  = (const float*)d_in[8];
  const float* b1  = (const float*)d_in[9];
  const float* w2  = (const float*)d_in[10];
  const float* b2  = (const float*)d_in[11];
  const float* g1  = (const float*)d_in[12];
  const float* be1 = (const float*)d_in[13];
  const float* g2  = (const float*)d_in[14];
  const float* be2 = (const float*)d_in[15];
  float* out = (float*)d_out;
  char* ws = (char*)d_ws;
  if (ws_size < WS_NEEDED) return;

  auto H = [&](size_t off) { return (h16*)(ws + off); };
  auto F = [&](size_t off) { return (float*)(ws + off); };
  auto I = [&](size_t off) { return (int*)(ws + off); };

  // zero atomic counters (counts[4] + cursor[4] contiguous)
  k_zero8<<<1, 64, 0, stream>>>(I(OFF_COUNTS));

  // input + weight splits
  k_split_in<<<BS*DM/4/256, 256, 0, stream>>>(src, pos,
      H(OFF_QKH), H(OFF_QKL), H(OFF_SRCH), H(OFF_SRCL));
  k_split2<<<3*DM*DM/4/256, 256, 0, stream>>>(w3, H(OFF_W3H), H(OFF_W3L), 64.0f, 3*DM*DM/4);
  k_split2<<<DM*DM/4/256, 256, 0, stream>>>(wo, H(OFF_WOH), H(OFF_WOL), 64.0f, DM*DM/4);

  // QKV projection (XCD-chunked 1D grid)
  k_qkv<<<dim3(1536), 256, 0, stream>>>(
      H(OFF_QKH), H(OFF_QKL), H(OFF_SRCH), H(OFF_SRCL), H(OFF_W3H), H(OFF_W3L), b3,
      H(OFF_QH), H(OFF_QL), H(OFF_KH), H(OFF_KL), H(OFF_VH), H(OFF_VL));

  // fused flash attention (one dispatch, XCD-swizzled)
  k_attn<<<dim3(NCHUNK*NBH), 256, 0, stream>>>(
      H(OFF_QH), H(OFF_QL), H(OFF_KH), H(OFF_KL), H(OFF_VH), H(OFF_VL),
      H(OFF_OH), H(OFF_OL));

  // out projection + LN1
  k_out<<<dim3(512), 256, 0, stream>>>(
      H(OFF_OH), H(OFF_OL), H(OFF_WOH), H(OFF_WOL), bo, F(OFF_ATT));
  k_ln<<<BS/4, 256, 0, stream>>>(src, F(OFF_ATT), g1, be1, F(OFF_X), H(OFF_XH), nullptr);

  // gate + expert bucketing (buckets padded to 128 rows)
  k_gate<<<BS/4, 256, 0, stream>>>(F(OFF_X), gw, gb, I(OFF_CHOSEN), I(OFF_COUNTS));
  k_offsets<<<1, 64, 0, stream>>>(I(OFF_COUNTS), I(OFF_EOFF));
  k_fill<<<(NPOS+255)/256, 256, 0, stream>>>(I(OFF_PLIST), NPOS);
  k_scatter<<<BS/256, 256, 0, stream>>>(I(OFF_CHOSEN), I(OFF_EOFF), I(OFF_CURSOR), I(OFF_PLIST));

  // MoE weights to f16 and bucketed expert FFN (128x64 core)
  k_tof16<<<NE*DFE*DM/4/256, 256, 0, stream>>>(w1, H(OFF_W1H), 64.0f, NE*DFE*DM/4);
  k_tof16<<<NE*DM*DFE/4/256, 256, 0, stream>>>(w2, H(OFF_W2H), 64.0f, NE*DM*DFE/4);
  k_e1<<<dim3(16, NPOS/128), 256, 0, stream>>>(
      H(OFF_XH), H(OFF_W1H), b1, I(OFF_PLIST), I(OFF_EOFF), H(OFF_HH));
  k_e2<<<dim3(16, NPOS/128), 256, 0, stream>>>(
      H(OFF_HH), H(OFF_W2H), b2, I(OFF_PLIST), I(OFF_EOFF), F(OFF_Y));

  // final LN2 -> output
  k_ln<<<BS/4, 256, 0, stream>>>(F(OFF_X), F(OFF_Y), g2, be2, nullptr, nullptr, out);
}

// Round 15
// 821.153 us; speedup vs baseline: 1.0457x; 1.0281x over previous
//
#include <hip/hip_runtime.h>
#include <cstdint>
#include <cstddef>

// ---------------------------------------------------------------------------
// TransformerEncoderLayer on MI355X (gfx950).
// Pre-gate GEMMs: f16 hi/lo split MFMA (3 mfma/product) — validated bit-equal
// to fp32 routing. QKV/out_proj: 128x128 split core, dbuf global_load_lds +
// XOR source swizzle; XCD mapping m-FAST (each XCD owns a fixed 4MB A-panel
// set, L2-resident; W streams via L3). MoE: bucketed f16 on a 128x128 dbuf
// gload_lds core (gather via per-lane global addresses).
// Attention: fused flash, swapped QK^T + in-register softmax + reg->reg P.
// Gate RNG: partitionable threefry, b1^b2 (VERIFIED round 5 — DO NOT TOUCH).
// ---------------------------------------------------------------------------

typedef _Float16 h16;
typedef h16 h16x8 __attribute__((ext_vector_type(8)));
typedef h16 h16x4 __attribute__((ext_vector_type(4)));
typedef __fp16 fp16x2 __attribute__((ext_vector_type(2)));   // cvt_pkrtz native type
typedef float f32x4 __attribute__((ext_vector_type(4)));
typedef uint32_t u32;

#define DM 1024
#define NH 16
#define HD 64
#define SEQ 1024
#define BB 8
#define BS (BB*SEQ)      /* 8192 tokens */
#define NBH (BB*NH)      /* 128 (b,h) pairs */
#define NE 4
#define DFE 1024
#define QB 64            /* query rows per attention chunk */
#define NCHUNK (SEQ/QB)  /* 16 */
#define SLDA 32          /* linear LDS stride (h16) for gload_lds slabs */
#define FLD 72           /* LDS stride for 64-wide flash tiles (64+8 pad) */
#define NPOS (68*128)    /* 8704: bucket capacity, 128-padded per expert */

#define MFMA16(a,b,c) __builtin_amdgcn_mfma_f32_16x16x32_f16(a,b,c,0,0,0)

// ---- workspace layout (bytes). E = one h16 plane of [8192][1024]. ----
static constexpr size_t E = (size_t)BS*DM*2;            // 16,777,216
static constexpr size_t OFF_QKH = 0;                    // qk split (dead after qkv)
static constexpr size_t OFF_QKL = E;
static constexpr size_t OFF_SRCH= 2*E;
static constexpr size_t OFF_SRCL= 3*E;
static constexpr size_t OFF_W3H = 4*E;
static constexpr size_t OFF_W3L = 4*E + (size_t)3*DM*DM*2;
static constexpr size_t OFF_WOH = 4*E + (size_t)6*DM*DM*2;
static constexpr size_t OFF_WOL = 4*E + (size_t)7*DM*DM*2;   // ends at 5E
static constexpr size_t OFF_QH  = 5*E;                  // Q,K [bh][s][d]; V^T [bh][d][s]
static constexpr size_t OFF_QL  = 6*E;
static constexpr size_t OFF_KH  = 7*E;
static constexpr size_t OFF_KL  = 8*E;
static constexpr size_t OFF_VH  = 9*E;
static constexpr size_t OFF_VL  = 10*E;
static constexpr size_t OFF_OH  = 0;                    // after flash (qk dead)
static constexpr size_t OFF_OL  = E;
static constexpr size_t OFF_ATT = 2*E;                  // fp32 (src splits dead)
static constexpr size_t OFF_X   = 5*E;                  // fp32 2E (Q,Ql dead)
static constexpr size_t OFF_XH  = 7*E;                  // f16 x*16 (Kh dead)
static constexpr size_t OFF_W1H = 8*E;                  // f16 (Kl dead)
static constexpr size_t OFF_W2H = 8*E + (size_t)NE*DFE*DM*2;  // ends at 9E
static constexpr size_t OFF_HH  = 9*E;                  // bucket h f16 [NPOS][1024] (V dead)
static constexpr size_t OFF_Y   = 11*E;                 // fp32 2E
static constexpr size_t OFF_CHOSEN = 13*E;
static constexpr size_t OFF_COUNTS = 13*E + 32768;
static constexpr size_t OFF_CURSOR = OFF_COUNTS + 16;
static constexpr size_t OFF_EOFF   = OFF_CURSOR + 16;
static constexpr size_t OFF_PLIST  = OFF_EOFF + 16;
static constexpr size_t WS_NEEDED  = OFF_PLIST + (size_t)NPOS*4;

// ---------------------------------------------------------------------------
__device__ __forceinline__ void store_split(h16* H, h16* L, size_t idx, float v) {
  h16 h = (h16)v;
  H[idx] = h;
  L[idx] = (h16)((v - (float)h) * 4096.0f);
}

__device__ __forceinline__ float wave_sum(float v) {
  #pragma unroll
  for (int o = 32; o; o >>= 1) v += __shfl_xor(v, o);
  return v;
}

// pack two floats to f16x2 (RTZ) and return the u32 word + the two f16 values
__device__ __forceinline__ u32 pk2(float a, float b, float& fa, float& fb) {
  union { fp16x2 h; u32 w; } u;
  u.h = __builtin_amdgcn_cvt_pkrtz(a, b);
  fa = (float)u.h[0];
  fb = (float)u.h[1];
  return u.w;
}
__device__ __forceinline__ u32 pk2w(float a, float b) {
  union { fp16x2 h; u32 w; } u;
  u.h = __builtin_amdgcn_cvt_pkrtz(a, b);
  return u.w;
}

// async global->LDS, 16B per lane; LDS dest = uniform base + lane*16
__device__ __forceinline__ void gload16(const void* g, void* l) {
  __builtin_amdgcn_global_load_lds(
      (const __attribute__((address_space(1))) u32*)g,
      (__attribute__((address_space(3))) u32*)l, 16, 0, 0);
}

// ---------------------------------------------------------------------------
// 128(M)x128(N) split-f16 MFMA core (round 14, verified): 4 waves 2x2,
// dbuf global_load_lds staging, XOR source swizzle.
// ---------------------------------------------------------------------------
__device__ __forceinline__ void gemm128x128_core(
    const h16* __restrict__ Ah, const h16* __restrict__ Al,
    const h16* __restrict__ Bh, const h16* __restrict__ Bl,
    int K, int lda, int ldb, int m0, int n0,
    f32x4 (&a1)[4][4], f32x4 (&a2)[4][4], h16* lds)
{
  constexpr int BUF = 4*128*SLDA;   // 16384 h16 = 32KB per buffer
  const int tid = threadIdx.x, lane = tid & 63, wid = tid >> 6;
  const int wr = (wid >> 1) * 64, wc = (wid & 1) * 64;
  const int lr16 = lane >> 2, lgrp = lane & 3;
  const int rA = wid*32 + lr16;               // rows +0 and +16
  const int sw = (rA >> 1) & 3;               // same for +16 (16>>1 = 8 ≡ 0 mod 4)
  const long gA0 = (long)(m0 + rA)      * lda + ((lgrp ^ sw) << 3);
  const long gA1 = (long)(m0 + rA + 16) * lda + ((lgrp ^ sw) << 3);
  const long gB0 = (long)(n0 + rA)      * ldb + ((lgrp ^ sw) << 3);
  const long gB1 = (long)(n0 + rA + 16) * ldb + ((lgrp ^ sw) << 3);
  const int oR0 = (wid*32)*SLDA, oR1 = (wid*32+16)*SLDA;
  const int fr = lane & 15, gi = lane >> 4;
  const int pcol = ((gi ^ ((lane >> 1) & 3)) << 3);
  const int nt = K >> 5;

  auto stage = [&](int t, int buf) {
    h16* base = lds + buf*BUF;
    h16* sAh = base;                h16* sAl = base + 128*SLDA;
    h16* sBh = base + 2*128*SLDA;   h16* sBl = base + 3*128*SLDA;
    const int k0 = t << 5;
    gload16(Ah + gA0 + k0, sAh + oR0);
    gload16(Ah + gA1 + k0, sAh + oR1);
    gload16(Al + gA0 + k0, sAl + oR0);
    gload16(Al + gA1 + k0, sAl + oR1);
    gload16(Bh + gB0 + k0, sBh + oR0);
    gload16(Bh + gB1 + k0, sBh + oR1);
    gload16(Bl + gB0 + k0, sBl + oR0);
    gload16(Bl + gB1 + k0, sBl + oR1);
  };

  stage(0, 0);
  __syncthreads();
  int cur = 0;
  for (int t = 0; t < nt; ++t) {
    if (t + 1 < nt) stage(t + 1, cur ^ 1);
    h16* base = lds + cur*BUF;
    h16* sAh = base;                h16* sAl = base + 128*SLDA;
    h16* sBh = base + 2*128*SLDA;   h16* sBl = base + 3*128*SLDA;
    h16x8 ah[4], al[4], bh[4], bl[4];
    #pragma unroll
    for (int i = 0; i < 4; ++i) {
      ah[i] = *(const h16x8*)(sAh + (wr + i*16 + fr)*SLDA + pcol);
      al[i] = *(const h16x8*)(sAl + (wr + i*16 + fr)*SLDA + pcol);
    }
    #pragma unroll
    for (int j = 0; j < 4; ++j) {
      bh[j] = *(const h16x8*)(sBh + (wc + j*16 + fr)*SLDA + pcol);
      bl[j] = *(const h16x8*)(sBl + (wc + j*16 + fr)*SLDA + pcol);
    }
    #pragma unroll
    for (int i = 0; i < 4; ++i)
      #pragma unroll
      for (int j = 0; j < 4; ++j) {
        a1[i][j] = MFMA16(ah[i], bh[j], a1[i][j]);
        a2[i][j] = MFMA16(ah[i], bl[j], a2[i][j]);
        a2[i][j] = MFMA16(al[i], bh[j], a2[i][j]);
      }
    __syncthreads();
    cur ^= 1;
  }
}

#define EPI_X \
  const int lane = threadIdx.x & 63, wid = threadIdx.x >> 6; \
  const int wr = (wid>>1)*64, wc = (wid&1)*64; \
  const int fr = lane & 15, rb = (lane>>4)*4;

// ---------------------------------------------------------------------------
// 128(M)x128(N) f16 single MFMA core for MoE: dbuf gload_lds, XOR swizzle,
// optional row gather on A (per-lane global src makes gather free).
// 16 MFMA : 8 ds_read per wave K-step; LDS 32KB (dbuf) -> ~5 blocks/CU.
// ---------------------------------------------------------------------------
template<bool GATHER>
__device__ __forceinline__ void hgemm128x128_core(
    const h16* __restrict__ A, const h16* __restrict__ B,
    int K, int lda, int ldb, int m0, int n0, const int* __restrict__ rowmap,
    f32x4 (&acc)[4][4], h16* lds)
{
  constexpr int BUF = 2*128*SLDA;   // 8192 h16 = 16KB per buffer
  const int tid = threadIdx.x, lane = tid & 63, wid = tid >> 6;
  const int wr = (wid >> 1) * 64, wc = (wid & 1) * 64;
  const int lr16 = lane >> 2, lgrp = lane & 3;
  const int rA = wid*32 + lr16;
  const int sw = (rA >> 1) & 3;
  long a0, a1;
  if (GATHER) {
    int t0 = rowmap[m0 + rA];      if (t0 < 0) t0 = 0;   // pad rows -> token 0 (masked later)
    int t1 = rowmap[m0 + rA + 16]; if (t1 < 0) t1 = 0;
    a0 = (long)t0 * lda + ((lgrp ^ sw) << 3);
    a1 = (long)t1 * lda + ((lgrp ^ sw) << 3);
  } else {
    a0 = (long)(m0 + rA)      * lda + ((lgrp ^ sw) << 3);
    a1 = (long)(m0 + rA + 16) * lda + ((lgrp ^ sw) << 3);
  }
  const long b0 = (long)(n0 + rA)      * ldb + ((lgrp ^ sw) << 3);
  const long b1 = (long)(n0 + rA + 16) * ldb + ((lgrp ^ sw) << 3);
  const int oR0 = (wid*32)*SLDA, oR1 = (wid*32+16)*SLDA;
  const int fr = lane & 15, gi = lane >> 4;
  const int pcol = ((gi ^ ((lane >> 1) & 3)) << 3);
  const int nt = K >> 5;

  auto stage = [&](int t, int buf) {
    h16* base = lds + buf*BUF;
    h16* sA = base;  h16* sB = base + 128*SLDA;
    const int k0 = t << 5;
    gload16(A + a0 + k0, sA + oR0);
    gload16(A + a1 + k0, sA + oR1);
    gload16(B + b0 + k0, sB + oR0);
    gload16(B + b1 + k0, sB + oR1);
  };

  stage(0, 0);
  __syncthreads();
  int cur = 0;
  for (int t = 0; t < nt; ++t) {
    if (t + 1 < nt) stage(t + 1, cur ^ 1);
    h16* base = lds + cur*BUF;
    h16* sA = base;  h16* sB = base + 128*SLDA;
    h16x8 a_[4], b_[4];
    #pragma unroll
    for (int i = 0; i < 4; ++i)
      a_[i] = *(const h16x8*)(sA + (wr + i*16 + fr)*SLDA + pcol);
    #pragma unroll
    for (int j = 0; j < 4; ++j)
      b_[j] = *(const h16x8*)(sB + (wc + j*16 + fr)*SLDA + pcol);
    #pragma unroll
    for (int i = 0; i < 4; ++i)
      #pragma unroll
      for (int j = 0; j < 4; ++j)
        acc[i][j] = MFMA16(a_[i], b_[j], acc[i][j]);
    __syncthreads();
    cur ^= 1;
  }
}

// ---------------------------------------------------------------------------
// prep kernels
// ---------------------------------------------------------------------------
__global__ void k_zero8(int* __restrict__ p) {
  if (threadIdx.x < 8) p[threadIdx.x] = 0;   // counts[4] + cursor[4]
}

__global__ void k_split_in(const float* __restrict__ src, const float* __restrict__ pos,
                           h16* __restrict__ qkH, h16* __restrict__ qkL,
                           h16* __restrict__ sH,  h16* __restrict__ sL) {
  int i = blockIdx.x*256 + threadIdx.x;
  float4 s = ((const float4*)src)[i];
  float4 p = ((const float4*)pos)[i];
  float sv[4] = {s.x, s.y, s.z, s.w};
  float qv[4] = {s.x+p.x, s.y+p.y, s.z+p.z, s.w+p.w};
  h16x4 sh, sl, qh, ql;
  #pragma unroll
  for (int q = 0; q < 4; ++q) {
    float xs = sv[q] * 16.0f; h16 hs = (h16)xs;
    sh[q] = hs; sl[q] = (h16)((xs - (float)hs) * 4096.0f);
    float xq = qv[q] * 16.0f; h16 hq = (h16)xq;
    qh[q] = hq; ql[q] = (h16)((xq - (float)hq) * 4096.0f);
  }
  ((h16x4*)sH)[i] = sh; ((h16x4*)sL)[i] = sl;
  ((h16x4*)qkH)[i] = qh; ((h16x4*)qkL)[i] = ql;
}

__global__ void k_split2(const float* __restrict__ a,
                         h16* __restrict__ H, h16* __restrict__ L, float scale, int n4) {
  int i = blockIdx.x*256 + threadIdx.x;
  if (i >= n4) return;
  float4 v = ((const float4*)a)[i];
  float vv[4] = {v.x, v.y, v.z, v.w};
  h16x4 hv, lv;
  #pragma unroll
  for (int q = 0; q < 4; ++q) {
    float x = vv[q] * scale;
    h16 h = (h16)x;
    hv[q] = h;
    lv[q] = (h16)((x - (float)h) * 4096.0f);
  }
  ((h16x4*)H)[i] = hv;
  ((h16x4*)L)[i] = lv;
}

__global__ void k_tof16(const float* __restrict__ a, h16* __restrict__ H, float scale, int n4) {
  int i = blockIdx.x*256 + threadIdx.x;
  if (i >= n4) return;
  float4 v = ((const float4*)a)[i];
  h16x4 hv;
  hv[0] = (h16)(v.x*scale); hv[1] = (h16)(v.y*scale);
  hv[2] = (h16)(v.z*scale); hv[3] = (h16)(v.w*scale);
  ((h16x4*)H)[i] = hv;
}

// ---------------------------------------------------------------------------
// QKV projection. XCD mapping m-FAST: xcd owns m-panels xcd*8..xcd*8+7 (4MB
// A working set, L2-resident whole kernel); n0 advances slowly (W via L3).
// ---------------------------------------------------------------------------
__global__ __launch_bounds__(256) void k_qkv(
    const h16* __restrict__ qkh, const h16* __restrict__ qkl,
    const h16* __restrict__ sh,  const h16* __restrict__ sl,
    const h16* __restrict__ Wh,  const h16* __restrict__ Wl, const float* __restrict__ bias,
    h16* __restrict__ Qh, h16* __restrict__ Ql, h16* __restrict__ Kh, h16* __restrict__ Kl,
    h16* __restrict__ Vh, h16* __restrict__ Vl)
{
  __shared__ h16 lds[2*4*128*SLDA];   // 65,536 B (double buffer)
  const int bid = blockIdx.x;                       // 0..1535
  const int xcd = bid & 7, loc = bid >> 3;          // loc 0..191
  const int m0 = (xcd*8 + (loc & 7)) * 128;         // fixed 8 panels per XCD
  const int n0 = (loc >> 3) * 128;                  // 24 n-panels, slow
  const bool isV = (n0 >= 2048);
  f32x4 a1[4][4] = {}; f32x4 a2[4][4] = {};
  gemm128x128_core(isV ? sh : qkh, isV ? sl : qkl, Wh, Wl,
                   1024, 1024, 1024, m0, n0, a1, a2, lds);
  EPI_X;
  #pragma unroll
  for (int i = 0; i < 4; ++i)
    #pragma unroll
    for (int j = 0; j < 4; ++j)
      #pragma unroll
      for (int r = 0; r < 4; ++r) {
        int row = m0 + wr + i*16 + rb + r;
        int col = n0 + wc + j*16 + fr;
        float c = (a1[i][j][r] + a2[i][j][r]*(1.0f/4096.0f)) * (1.0f/1024.0f) + bias[col];
        int b = row >> 10, s = row & 1023;
        int cc = col & 1023, h = cc >> 6, d = cc & 63;
        long bh = (long)b*NH + h;
        float cs = c * 16.0f;
        if (col < 1024)      store_split(Qh, Ql, (bh*SEQ + s)*HD + d, cs);
        else if (col < 2048) store_split(Kh, Kl, (bh*SEQ + s)*HD + d, cs);
        else                 store_split(Vh, Vl, (bh*HD + d)*SEQ + s, cs);
      }
}

// ---------------------------------------------------------------------------
// Fused flash attention (round 12, verified): swapped QK^T, in-reg softmax,
// reg->reg P via cvt_pkrtz + shfl.
// ---------------------------------------------------------------------------
__global__ __launch_bounds__(256) void k_attn(
    const h16* __restrict__ Qh, const h16* __restrict__ Ql,
    const h16* __restrict__ Kh, const h16* __restrict__ Kl,
    const h16* __restrict__ Vh, const h16* __restrict__ Vl,
    h16* __restrict__ Oh, h16* __restrict__ Ol)
{
  __shared__ h16 lds[4*64*FLD];   // 36,864 B (K h/l + V h/l)
  h16* sKh = lds;            h16* sKl = lds + 64*FLD;
  h16* sVh = lds + 2*64*FLD; h16* sVl = lds + 3*64*FLD;
  const int bid = blockIdx.x;                  // 0..2047
  const int swz = (bid & 7) * 256 + (bid >> 3);
  const int bh = swz >> 4;
  const int q0 = (swz & 15) * QB;
  const int tid = threadIdx.x, lane = tid & 63, w = tid >> 6;
  const int fr = lane & 15, hg = lane >> 4;   // 0..3
  const int kg = hg << 3;
  const long qbase = ((long)bh*SEQ + q0 + w*16 + fr) * HD;
  h16x8 qh[2], ql[2];
  qh[0] = *(const h16x8*)(Qh + qbase + kg);
  qh[1] = *(const h16x8*)(Qh + qbase + 32 + kg);
  ql[0] = *(const h16x8*)(Ql + qbase + kg);
  ql[1] = *(const h16x8*)(Ql + qbase + 32 + kg);
  f32x4 o1[4] = {}, o2[4] = {};      // O[q=4hg+r][d=16jd+fr]
  float mrow = -3.0e38f, lrow = 0.f; // for q-row = w*16 + fr
  const int srow = tid >> 2, skc = (tid & 3) << 4;
  const long kbase = ((long)bh*SEQ + srow) * HD + skc;
  const long vbase = ((long)bh*HD + srow) * SEQ + skc;
  const int srcA = fr + ((hg & 1) << 5);
  const int srcB = srcA + 16;
  for (int kt = 0; kt < NCHUNK; ++kt) {
    const int n0 = kt * QB;
    __syncthreads();
    {
      const long ka = kbase + (long)n0*HD;
      *(uint4*)(sKh + srow*FLD + skc)     = *(const uint4*)(Kh + ka);
      *(uint4*)(sKh + srow*FLD + skc + 8) = *(const uint4*)(Kh + ka + 8);
      *(uint4*)(sKl + srow*FLD + skc)     = *(const uint4*)(Kl + ka);
      *(uint4*)(sKl + srow*FLD + skc + 8) = *(const uint4*)(Kl + ka + 8);
      const long va = vbase + n0;
      *(uint4*)(sVh + srow*FLD + skc)     = *(const uint4*)(Vh + va);
      *(uint4*)(sVh + srow*FLD + skc + 8) = *(const uint4*)(Vh + va + 8);
      *(uint4*)(sVl + srow*FLD + skc)     = *(const uint4*)(Vl + va);
      *(uint4*)(sVl + srow*FLD + skc + 8) = *(const uint4*)(Vl + va + 8);
    }
    __syncthreads();
    f32x4 s1[4] = {}, s2[4] = {};
    #pragma unroll
    for (int ks = 0; ks < 2; ++ks)
      #pragma unroll
      for (int j = 0; j < 4; ++j) {
        h16x8 kh = *(const h16x8*)(sKh + (j*16 + fr)*FLD + ks*32 + kg);
        h16x8 kl = *(const h16x8*)(sKl + (j*16 + fr)*FLD + ks*32 + kg);
        s1[j] = MFMA16(kh, qh[ks], s1[j]);
        s2[j] = MFMA16(kh, ql[ks], s2[j]);
        s2[j] = MFMA16(kl, qh[ks], s2[j]);
      }
    float p[4][4];
    float tmax = -3.0e38f;
    #pragma unroll
    for (int j = 0; j < 4; ++j)
      #pragma unroll
      for (int r = 0; r < 4; ++r) {
        float sc = (s1[j][r] + s2[j][r]*(1.0f/4096.0f)) * (0.125f/256.0f);
        p[j][r] = sc;
        tmax = fmaxf(tmax, sc);
      }
    tmax = fmaxf(tmax, __shfl_xor(tmax, 16));
    tmax = fmaxf(tmax, __shfl_xor(tmax, 32));
    float mn = fmaxf(mrow, tmax);
    float sclf = __expf(mrow - mn);
    mrow = mn;
    float psum = 0.f;
    #pragma unroll
    for (int j = 0; j < 4; ++j)
      #pragma unroll
      for (int r = 0; r < 4; ++r) { float e = __expf(p[j][r] - mn); p[j][r] = e; psum += e; }
    psum += __shfl_xor(psum, 16);
    psum += __shfl_xor(psum, 32);
    lrow = lrow*sclf + psum;
    #pragma unroll
    for (int r = 0; r < 4; ++r) {
      float sq = __shfl(sclf, hg*4 + r);
      #pragma unroll
      for (int jd = 0; jd < 4; ++jd) { o1[jd][r] *= sq; o2[jd][r] *= sq; }
    }
    u32 hp[4][2], lp[4][2];
    #pragma unroll
    for (int j = 0; j < 4; ++j)
      #pragma unroll
      for (int rp = 0; rp < 2; ++rp) {
        float a = p[j][2*rp]   * 512.0f;
        float b = p[j][2*rp+1] * 512.0f;
        float fa, fb;
        hp[j][rp] = pk2(a, b, fa, fb);
        lp[j][rp] = pk2w((a - fa) * 4096.0f, (b - fb) * 4096.0f);
      }
    #pragma unroll
    for (int ks = 0; ks < 2; ++ks) {
      const int j0 = 2*ks, j1 = 2*ks + 1;
      u32 hA0 = (u32)__shfl((int)hp[j0][0], srcA), hA1 = (u32)__shfl((int)hp[j0][1], srcA);
      u32 hB0 = (u32)__shfl((int)hp[j0][0], srcB), hB1 = (u32)__shfl((int)hp[j0][1], srcB);
      u32 hC0 = (u32)__shfl((int)hp[j1][0], srcA), hC1 = (u32)__shfl((int)hp[j1][1], srcA);
      u32 hD0 = (u32)__shfl((int)hp[j1][0], srcB), hD1 = (u32)__shfl((int)hp[j1][1], srcB);
      u32 lA0 = (u32)__shfl((int)lp[j0][0], srcA), lA1 = (u32)__shfl((int)lp[j0][1], srcA);
      u32 lB0 = (u32)__shfl((int)lp[j0][0], srcB), lB1 = (u32)__shfl((int)lp[j0][1], srcB);
      u32 lC0 = (u32)__shfl((int)lp[j1][0], srcA), lC1 = (u32)__shfl((int)lp[j1][1], srcA);
      u32 lD0 = (u32)__shfl((int)lp[j1][0], srcB), lD1 = (u32)__shfl((int)lp[j1][1], srcB);
      const bool hij = (hg & 2) != 0;
      union { u32 w[4]; h16x8 v; } pa, pb;
      pa.w[0] = hij ? hC0 : hA0;  pa.w[1] = hij ? hC1 : hA1;
      pa.w[2] = hij ? hD0 : hB0;  pa.w[3] = hij ? hD1 : hB1;
      pb.w[0] = hij ? lC0 : lA0;  pb.w[1] = hij ? lC1 : lA1;
      pb.w[2] = hij ? lD0 : lB0;  pb.w[3] = hij ? lD1 : lB1;
      #pragma unroll
      for (int jd = 0; jd < 4; ++jd) {
        h16x8 vh = *(const h16x8*)(sVh + (jd*16 + fr)*FLD + ks*32 + kg);
        h16x8 vl = *(const h16x8*)(sVl + (jd*16 + fr)*FLD + ks*32 + kg);
        o1[jd] = MFMA16(pa.v, vh, o1[jd]);
        o2[jd] = MFMA16(pa.v, vl, o2[jd]);
        o2[jd] = MFMA16(pb.v, vh, o2[jd]);
      }
    }
  }
  float lq[4];
  #pragma unroll
  for (int r = 0; r < 4; ++r) lq[r] = __shfl(lrow, hg*4 + r);
  const int b = bh >> 4, h = bh & 15;
  #pragma unroll
  for (int jd = 0; jd < 4; ++jd)
    #pragma unroll
    for (int r = 0; r < 4; ++r) {
      int qrow = q0 + w*16 + hg*4 + r;
      int d = jd*16 + fr;
      float ov = (o1[jd][r] + o2[jd][r]*(1.0f/4096.0f)) / (512.0f*16.0f*lq[r]);
      store_split(Oh, Ol, ((long)b*SEQ + qrow)*DM + h*HD + d, ov*16.0f);
    }
}

// out_proj: XCD mapping m-FAST (512 = 8 XCD x (8 m x 8 n0))
__global__ __launch_bounds__(256) void k_out(
    const h16* __restrict__ Oh, const h16* __restrict__ Ol,
    const h16* __restrict__ Wh, const h16* __restrict__ Wl,
    const float* __restrict__ bias, float* __restrict__ attn)
{
  __shared__ h16 lds[2*4*128*SLDA];
  const int bid = blockIdx.x;                       // 0..511
  const int xcd = bid & 7, loc = bid >> 3;          // loc 0..63
  const int m0 = (xcd*8 + (loc & 7)) * 128;
  const int n0 = (loc >> 3) * 128;
  f32x4 a1[4][4] = {}; f32x4 a2[4][4] = {};
  gemm128x128_core(Oh, Ol, Wh, Wl, 1024, 1024, 1024, m0, n0, a1, a2, lds);
  EPI_X;
  #pragma unroll
  for (int i = 0; i < 4; ++i)
    #pragma unroll
    for (int j = 0; j < 4; ++j)
      #pragma unroll
      for (int r = 0; r < 4; ++r) {
        int row = m0 + wr + i*16 + rb + r;
        int col = n0 + wc + j*16 + fr;
        attn[(long)row*DM + col] =
            (a1[i][j][r] + a2[i][j][r]*(1.0f/4096.0f)) * (1.0f/1024.0f) + bias[col];
      }
}

// LayerNorm of (A + Badd): optional fp32 out, f16(x*16) out, direct out
__global__ __launch_bounds__(256) void k_ln(
    const float* __restrict__ A, const float* __restrict__ Badd,
    const float* __restrict__ g, const float* __restrict__ be,
    float* __restrict__ xout, h16* __restrict__ xh, float* __restrict__ dout)
{
  int wave = threadIdx.x >> 6, lane = threadIdx.x & 63;
  long row = (long)blockIdx.x*4 + wave;
  const float* ar = A + row*DM; const float* br = Badd + row*DM;
  float v[16]; float s = 0.0f;
  #pragma unroll
  for (int p = 0; p < 4; ++p) {
    int d = p*256 + lane*4;
    float4 a = *(const float4*)(ar + d);
    float4 b = *(const float4*)(br + d);
    float t0=a.x+b.x, t1=a.y+b.y, t2=a.z+b.z, t3=a.w+b.w;
    v[4*p+0]=t0; v[4*p+1]=t1; v[4*p+2]=t2; v[4*p+3]=t3;
    s += t0+t1+t2+t3;
  }
  s = wave_sum(s);
  float m = s * (1.0f/1024.0f);
  float q = 0.0f;
  #pragma unroll
  for (int i = 0; i < 16; ++i) { float dd = v[i]-m; q += dd*dd; }
  q = wave_sum(q);
  float rs = (float)(1.0 / sqrt((double)(q * (1.0f/1024.0f) + 1e-5f)));
  #pragma unroll
  for (int p = 0; p < 4; ++p) {
    int d = p*256 + lane*4;
    float4 gv = *(const float4*)(g + d);
    float4 bv = *(const float4*)(be + d);
    float y0 = (v[4*p+0]-m)*rs*gv.x + bv.x;
    float y1 = (v[4*p+1]-m)*rs*gv.y + bv.y;
    float y2 = (v[4*p+2]-m)*rs*gv.z + bv.z;
    float y3 = (v[4*p+3]-m)*rs*gv.w + bv.w;
    if (xout) { float4 o = {y0,y1,y2,y3}; *(float4*)(xout + row*DM + d) = o; }
    if (xh) {
      h16x4 hv; hv[0]=(h16)(y0*16.f); hv[1]=(h16)(y1*16.f);
      hv[2]=(h16)(y2*16.f); hv[3]=(h16)(y3*16.f);
      *(h16x4*)(xh + row*DM + d) = hv;
    }
    if (dout) { float4 o = {y0,y1,y2,y3}; *(float4*)(dout + row*DM + d) = o; }
  }
}

// ---------------------------------------------------------------------------
// threefry2x32 (key=[0,42]) -> gumbel -> argmax. VERIFIED round 5 — DO NOT TOUCH.
// partitionable bits = b1 ^ b2, counter = (0, i).
// ---------------------------------------------------------------------------
__device__ __forceinline__ void threefry(u32 x0, u32 x1, u32& y0, u32& y1) {
  const u32 ks0 = 0u, ks1 = 42u, ks2 = 0x1BD11BDAu ^ 42u;
  x0 += ks0; x1 += ks1;
  #define TF_R(r) { x0 += x1; x1 = (x1 << r) | (x1 >> (32 - r)); x1 ^= x0; }
  TF_R(13) TF_R(15) TF_R(26) TF_R(6)  x0 += ks1; x1 += ks2 + 1u;
  TF_R(17) TF_R(29) TF_R(16) TF_R(24) x0 += ks2; x1 += ks0 + 2u;
  TF_R(13) TF_R(15) TF_R(26) TF_R(6)  x0 += ks0; x1 += ks1 + 3u;
  TF_R(17) TF_R(29) TF_R(16) TF_R(24) x0 += ks1; x1 += ks2 + 4u;
  TF_R(13) TF_R(15) TF_R(26) TF_R(6)  x0 += ks2; x1 += ks0 + 5u;
  #undef TF_R
  y0 = x0; y1 = x1;
}

__device__ __forceinline__ float gumbel_from(u32 bits) {
  float f = __uint_as_float((bits >> 9) | 0x3F800000u) - 1.0f;
  float u = (f > 0.0f) ? f : 1.17549435e-38f;
  float nl = (float)(-log((double)u));
  return -(float)log((double)nl);
}

__global__ __launch_bounds__(256) void k_gate(
    const float* __restrict__ x, const float* __restrict__ gw,
    const float* __restrict__ gb, int* __restrict__ chosen, int* __restrict__ counts)
{
  int wave = threadIdx.x >> 6, lane = threadIdx.x & 63;
  long t = (long)blockIdx.x*4 + wave;
  const float* xr = x + t*DM;
  float p[4] = {0.f,0.f,0.f,0.f};
  #pragma unroll
  for (int pp = 0; pp < 4; ++pp) {
    int d = pp*256 + lane*4;
    float4 xv = *(const float4*)(xr + d);
    #pragma unroll
    for (int e = 0; e < 4; ++e) {
      float4 gv = *(const float4*)(gw + e*DM + d);
      p[e] += xv.x*gv.x + xv.y*gv.y + xv.z*gv.z + xv.w*gv.w;
    }
  }
  #pragma unroll
  for (int e = 0; e < 4; ++e) p[e] = wave_sum(p[e]);
  if (lane == 0) {
    float best = -3.0e38f; int arg = 0;
    #pragma unroll
    for (int e = 0; e < 4; ++e) {
      float logit = p[e] + gb[e];
      u32 j = (u32)(4*t + e);
      u32 y0, y1;
      threefry(0u, j, y0, y1);
      float v = gumbel_from(y0 ^ y1) + logit;
      if (v > best) { best = v; arg = e; }
    }
    chosen[(int)t] = arg;
    atomicAdd(&counts[arg], 1);
  }
}

__global__ void k_offsets(const int* __restrict__ counts, int* __restrict__ eoff) {
  if (threadIdx.x == 0 && blockIdx.x == 0) {
    int o = 0;
    for (int e = 0; e < 4; ++e) { eoff[e] = o; o += (counts[e] + 127) & ~127; }
  }
}

__global__ void k_fill(int* __restrict__ p, int n) {
  int i = blockIdx.x*256 + threadIdx.x;
  if (i < n) p[i] = -1;
}

__global__ void k_scatter(const int* __restrict__ chosen, const int* __restrict__ eoff,
                          int* __restrict__ cursor, int* __restrict__ plist) {
  int t = blockIdx.x*256 + threadIdx.x;
  if (t >= BS) return;
  int e = chosen[t];
  int slot = atomicAdd(&cursor[e], 1);
  plist[eoff[e] + slot] = t;
}

// MoE layer 1 (gathered rows, 128x128 dbuf core): h = relu(x.w1[e]^T + b1[e])
__global__ __launch_bounds__(256) void k_e1(
    const h16* __restrict__ Xh, const h16* __restrict__ W1, const float* __restrict__ b1,
    const int* __restrict__ plist, const int* __restrict__ eoff, h16* __restrict__ Hh)
{
  __shared__ h16 lds[2*2*128*SLDA];   // 32KB
  const int n0 = blockIdx.x*128, m0 = blockIdx.y*128;
  const int e = (m0 >= eoff[1]) + (m0 >= eoff[2]) + (m0 >= eoff[3]);
  f32x4 acc[4][4] = {};
  hgemm128x128_core<true>(Xh, W1 + (long)e*DFE*DM, 1024, 1024, 1024, m0, n0, plist, acc, lds);
  EPI_X;
  #pragma unroll
  for (int i = 0; i < 4; ++i)
    #pragma unroll
    for (int j = 0; j < 4; ++j)
      #pragma unroll
      for (int r = 0; r < 4; ++r) {
        int row = m0 + wr + i*16 + rb + r;
        int col = n0 + wc + j*16 + fr;
        float c = acc[i][j][r] * (1.0f/1024.0f) + b1[e*DFE + col];
        c = fmaxf(c, 0.0f);
        Hh[(long)row*DFE + col] = (h16)(c * 16.0f);
      }
}

// MoE layer 2 (bucket rows, 128x128 dbuf core, scatter out)
__global__ __launch_bounds__(256) void k_e2(
    const h16* __restrict__ Hh, const h16* __restrict__ W2, const float* __restrict__ b2,
    const int* __restrict__ plist, const int* __restrict__ eoff, float* __restrict__ y)
{
  __shared__ h16 lds[2*2*128*SLDA];   // 32KB
  const int n0 = blockIdx.x*128, m0 = blockIdx.y*128;
  const int e = (m0 >= eoff[1]) + (m0 >= eoff[2]) + (m0 >= eoff[3]);
  f32x4 acc[4][4] = {};
  hgemm128x128_core<false>(Hh, W2 + (long)e*DM*DFE, 1024, DFE, DFE, m0, n0, nullptr, acc, lds);
  EPI_X;
  #pragma unroll
  for (int i = 0; i < 4; ++i)
    #pragma unroll
    for (int j = 0; j < 4; ++j)
      #pragma unroll
      for (int r = 0; r < 4; ++r) {
        int row = m0 + wr + i*16 + rb + r;
        int col = n0 + wc + j*16 + fr;
        int t = plist[row];
        if (t >= 0)
          y[(long)t*DM + col] = acc[i][j][r] * (1.0f/1024.0f) + b2[e*DM + col];
      }
}

// ---------------------------------------------------------------------------
extern "C" void kernel_launch(void* const* d_in, const int* in_sizes, int n_in,
                              void* d_out, int out_size, void* d_ws, size_t ws_size,
                              hipStream_t stream) {
  const float* src = (const float*)d_in[0];
  const float* pos = (const float*)d_in[1];
  const float* w3  = (const float*)d_in[2];
  const float* b3  = (const float*)d_in[3];
  const float* wo  = (const float*)d_in[4];
  const float* bo  = (const float*)d_in[5];
  const float* gw  = (const float*)d_in[6];
  const float* gb  = (const float*)d_in[7];
  const float* w1  = (const float*)d_in[8];
  const float* b1  = (const float*)d_in[9];
  const float* w2  = (const float*)d_in[10];
  const float* b2  = (const float*)d_in[11];
  const float* g1  = (const float*)d_in[12];
  const float* be1 = (const float*)d_in[13];
  const float* g2  = (const float*)d_in[14];
  const float* be2 = (const float*)d_in[15];
  float* out = (float*)d_out;
  char* ws = (char*)d_ws;
  if (ws_size < WS_NEEDED) return;

  auto H = [&](size_t off) { return (h16*)(ws + off); };
  auto F = [&](size_t off) { return (float*)(ws + off); };
  auto I = [&](size_t off) { return (int*)(ws + off); };

  // zero atomic counters (counts[4] + cursor[4] contiguous)
  k_zero8<<<1, 64, 0, stream>>>(I(OFF_COUNTS));

  // input + weight splits
  k_split_in<<<BS*DM/4/256, 256, 0, stream>>>(src, pos,
      H(OFF_QKH), H(OFF_QKL), H(OFF_SRCH), H(OFF_SRCL));
  k_split2<<<3*DM*DM/4/256, 256, 0, stream>>>(w3, H(OFF_W3H), H(OFF_W3L), 64.0f, 3*DM*DM/4);
  k_split2<<<DM*DM/4/256, 256, 0, stream>>>(wo, H(OFF_WOH), H(OFF_WOL), 64.0f, DM*DM/4);

  // QKV projection (XCD m-fast mapping)
  k_qkv<<<dim3(1536), 256, 0, stream>>>(
      H(OFF_QKH), H(OFF_QKL), H(OFF_SRCH), H(OFF_SRCL), H(OFF_W3H), H(OFF_W3L), b3,
      H(OFF_QH), H(OFF_QL), H(OFF_KH), H(OFF_KL), H(OFF_VH), H(OFF_VL));

  // fused flash attention (one dispatch, XCD-swizzled)
  k_attn<<<dim3(NCHUNK*NBH), 256, 0, stream>>>(
      H(OFF_QH), H(OFF_QL), H(OFF_KH), H(OFF_KL), H(OFF_VH), H(OFF_VL),
      H(OFF_OH), H(OFF_OL));

  // out projection + LN1
  k_out<<<dim3(512), 256, 0, stream>>>(
      H(OFF_OH), H(OFF_OL), H(OFF_WOH), H(OFF_WOL), bo, F(OFF_ATT));
  k_ln<<<BS/4, 256, 0, stream>>>(src, F(OFF_ATT), g1, be1, F(OFF_X), H(OFF_XH), nullptr);

  // gate + expert bucketing (buckets padded to 128 rows)
  k_gate<<<BS/4, 256, 0, stream>>>(F(OFF_X), gw, gb, I(OFF_CHOSEN), I(OFF_COUNTS));
  k_offsets<<<1, 64, 0, stream>>>(I(OFF_COUNTS), I(OFF_EOFF));
  k_fill<<<(NPOS+255)/256, 256, 0, stream>>>(I(OFF_PLIST), NPOS);
  k_scatter<<<BS/256, 256, 0, stream>>>(I(OFF_CHOSEN), I(OFF_EOFF), I(OFF_CURSOR), I(OFF_PLIST));

  // MoE weights to f16 and bucketed expert FFN (128x128 dbuf core)
  k_tof16<<<NE*DFE*DM/4/256, 256, 0, stream>>>(w1, H(OFF_W1H), 64.0f, NE*DFE*DM/4);
  k_tof16<<<NE*DM*DFE/4/256, 256, 0, stream>>>(w2, H(OFF_W2H), 64.0f, NE*DM*DFE/4);
  k_e1<<<dim3(DFE/128, NPOS/128), 256, 0, stream>>>(
      H(OFF_XH), H(OFF_W1H), b1, I(OFF_PLIST), I(OFF_EOFF), H(OFF_HH));
  k_e2<<<dim3(DM/128, NPOS/128), 256, 0, stream>>>(
      H(OFF_HH), H(OFF_W2H), b2, I(OFF_PLIST), I(OFF_EOFF), F(OFF_Y));

  // final LN2 -> output
  k_ln<<<BS/4, 256, 0, stream>>>(F(OFF_X), F(OFF_Y), g2, be2, nullptr, nullptr, out);
}

// Round 16
// 787.278 us; speedup vs baseline: 1.0907x; 1.0430x over previous
//
#include <hip/hip_runtime.h>
#include <cstdint>
#include <cstddef>

// ---------------------------------------------------------------------------
// TransformerEncoderLayer on MI355X (gfx950).
// Split format (NEW round 16): x ~ (hi + lo)/s with lo stored UNSCALED
// (residual in f16; subnormal flush affects only ~0.6% tiniest residuals,
// ~3e-7 relative). All 3 split MFMAs accumulate into ONE accumulator.
// QKV/out_proj: 256x256 tile, 512 thr / 8 waves, single-buffer gload_lds
// (halves L2/L3 traffic vs 128^2 — the measured bound), XOR source swizzle,
// m-fast XCD mapping. Attention: fused flash, swapped QK^T, in-reg softmax.
// Gate RNG: partitionable threefry, b1^b2 (VERIFIED round 5 — DO NOT TOUCH).
// MoE: bucketed f16 128x128 dbuf core (round 15, verified).
// ---------------------------------------------------------------------------

typedef _Float16 h16;
typedef h16 h16x8 __attribute__((ext_vector_type(8)));
typedef h16 h16x4 __attribute__((ext_vector_type(4)));
typedef __fp16 fp16x2 __attribute__((ext_vector_type(2)));
typedef float f32x4 __attribute__((ext_vector_type(4)));
typedef uint32_t u32;

#define DM 1024
#define NH 16
#define HD 64
#define SEQ 1024
#define BB 8
#define BS (BB*SEQ)
#define NBH (BB*NH)
#define NE 4
#define DFE 1024
#define QB 64
#define NCHUNK (SEQ/QB)
#define SLDA 32          /* linear LDS stride (h16) for gload_lds slabs */
#define FLD 72           /* LDS stride for 64-wide flash tiles */
#define NPOS (68*128)

#define MFMA16(a,b,c) __builtin_amdgcn_mfma_f32_16x16x32_f16(a,b,c,0,0,0)

// ---- workspace layout (bytes). E = one h16 plane of [8192][1024]. ----
static constexpr size_t E = (size_t)BS*DM*2;
static constexpr size_t OFF_QKH = 0;
static constexpr size_t OFF_QKL = E;
static constexpr size_t OFF_SRCH= 2*E;
static constexpr size_t OFF_SRCL= 3*E;
static constexpr size_t OFF_W3H = 4*E;
static constexpr size_t OFF_W3L = 4*E + (size_t)3*DM*DM*2;
static constexpr size_t OFF_WOH = 4*E + (size_t)6*DM*DM*2;
static constexpr size_t OFF_WOL = 4*E + (size_t)7*DM*DM*2;
static constexpr size_t OFF_QH  = 5*E;
static constexpr size_t OFF_QL  = 6*E;
static constexpr size_t OFF_KH  = 7*E;
static constexpr size_t OFF_KL  = 8*E;
static constexpr size_t OFF_VH  = 9*E;
static constexpr size_t OFF_VL  = 10*E;
static constexpr size_t OFF_OH  = 0;
static constexpr size_t OFF_OL  = E;
static constexpr size_t OFF_ATT = 2*E;
static constexpr size_t OFF_X   = 5*E;
static constexpr size_t OFF_XH  = 7*E;
static constexpr size_t OFF_W1H = 8*E;
static constexpr size_t OFF_W2H = 8*E + (size_t)NE*DFE*DM*2;
static constexpr size_t OFF_HH  = 9*E;
static constexpr size_t OFF_Y   = 11*E;
static constexpr size_t OFF_CHOSEN = 13*E;
static constexpr size_t OFF_COUNTS = 13*E + 32768;
static constexpr size_t OFF_CURSOR = OFF_COUNTS + 16;
static constexpr size_t OFF_EOFF   = OFF_CURSOR + 16;
static constexpr size_t OFF_PLIST  = OFF_EOFF + 16;
static constexpr size_t WS_NEEDED  = OFF_PLIST + (size_t)NPOS*4;

// ---------------------------------------------------------------------------
// merged-format split store: lo = residual, UNSCALED
__device__ __forceinline__ void store_split(h16* H, h16* L, size_t idx, float v) {
  h16 h = (h16)v;
  H[idx] = h;
  L[idx] = (h16)(v - (float)h);
}

__device__ __forceinline__ float wave_sum(float v) {
  #pragma unroll
  for (int o = 32; o; o >>= 1) v += __shfl_xor(v, o);
  return v;
}

__device__ __forceinline__ u32 pk2(float a, float b, float& fa, float& fb) {
  union { fp16x2 h; u32 w; } u;
  u.h = __builtin_amdgcn_cvt_pkrtz(a, b);
  fa = (float)u.h[0];
  fb = (float)u.h[1];
  return u.w;
}
__device__ __forceinline__ u32 pk2w(float a, float b) {
  union { fp16x2 h; u32 w; } u;
  u.h = __builtin_amdgcn_cvt_pkrtz(a, b);
  return u.w;
}

__device__ __forceinline__ void gload16(const void* g, void* l) {
  __builtin_amdgcn_global_load_lds(
      (const __attribute__((address_space(1))) u32*)g,
      (__attribute__((address_space(3))) u32*)l, 16, 0, 0);
}

// ---------------------------------------------------------------------------
// 256x256 split-f16 MERGED-ACC core. 512 thr / 8 waves (2m x 4n), wave tile
// 128x64 (8x4 frags), ONE f32x4 acc[8][4] = 128 regs. Single 64KB buffer:
// 4 planes (Ah,Al,Bh,Bl) x [256][SLDA]. Each wave stages one half-plane
// (8 gload16). 96 MFMA : 24 ds_read per wave K-step. XOR source swizzle.
// ---------------------------------------------------------------------------
__device__ __forceinline__ void gemm256_core(
    const h16* __restrict__ Ah, const h16* __restrict__ Al,
    const h16* __restrict__ Bh, const h16* __restrict__ Bl,
    int K, int lda, int ldb, int m0, int n0,
    f32x4 (&acc)[8][4], h16* lds)
{
  const int tid = threadIdx.x, lane = tid & 63, wid = tid >> 6;  // 0..7
  const int wr = (wid >> 2) * 128, wc = (wid & 3) * 64;
  const int lr16 = lane >> 2, lgrp = lane & 3;
  // staging: wave -> plane (wid>>1: 0 Ah,1 Al,2 Bh,3 Bl), half (wid&1)*128
  const int plane = wid >> 1;
  const int half  = (wid & 1) * 128;
  const int sw = (lr16 >> 1) & 3;
  const h16* gp = (plane == 0) ? Ah : (plane == 1) ? Al : (plane == 2) ? Bh : Bl;
  const int ld  = (plane < 2) ? lda : ldb;
  const long g0 = (long)((plane < 2 ? m0 : n0) + half + lr16) * ld + ((lgrp ^ sw) << 3);
  h16* lbase = lds + plane*(256*SLDA) + half*SLDA;
  // read addressing
  h16* sAh_ = lds;
  h16* sAl_ = lds + 256*SLDA;
  h16* sBh_ = lds + 2*256*SLDA;
  h16* sBl_ = lds + 3*256*SLDA;
  const int fr = lane & 15, gi = lane >> 4;
  const int pcol = ((gi ^ ((lane >> 1) & 3)) << 3);
  const int nt = K >> 5;
  for (int t = 0; t < nt; ++t) {
    const long k0 = (long)t << 5;
    #pragma unroll
    for (int g = 0; g < 8; ++g)
      gload16(gp + g0 + (long)(g*16)*ld + k0, lbase + (g*16)*SLDA);
    __syncthreads();                       // vmcnt(0) drain -> tile ready
    h16x8 bh[4], bl[4];
    #pragma unroll
    for (int j = 0; j < 4; ++j) {
      bh[j] = *(const h16x8*)(sBh_ + (wc + j*16 + fr)*SLDA + pcol);
      bl[j] = *(const h16x8*)(sBl_ + (wc + j*16 + fr)*SLDA + pcol);
    }
    #pragma unroll
    for (int i = 0; i < 8; ++i) {
      h16x8 ah = *(const h16x8*)(sAh_ + (wr + i*16 + fr)*SLDA + pcol);
      h16x8 al = *(const h16x8*)(sAl_ + (wr + i*16 + fr)*SLDA + pcol);
      #pragma unroll
      for (int j = 0; j < 4; ++j) {
        acc[i][j] = MFMA16(ah, bh[j], acc[i][j]);
        acc[i][j] = MFMA16(ah, bl[j], acc[i][j]);
        acc[i][j] = MFMA16(al, bh[j], acc[i][j]);
      }
    }
    __syncthreads();                       // readers done before restage
  }
}

#define EPI_256 \
  const int lane = threadIdx.x & 63, wid = threadIdx.x >> 6; \
  const int wr = (wid>>2)*128, wc = (wid&3)*64; \
  const int fr = lane & 15, rb = (lane>>4)*4;

#define EPI_X \
  const int lane = threadIdx.x & 63, wid = threadIdx.x >> 6; \
  const int wr = (wid>>1)*64, wc = (wid&1)*64; \
  const int fr = lane & 15, rb = (lane>>4)*4;

// ---------------------------------------------------------------------------
// 128x128 f16 single MFMA core for MoE (round 15, verified).
// ---------------------------------------------------------------------------
template<bool GATHER>
__device__ __forceinline__ void hgemm128x128_core(
    const h16* __restrict__ A, const h16* __restrict__ B,
    int K, int lda, int ldb, int m0, int n0, const int* __restrict__ rowmap,
    f32x4 (&acc)[4][4], h16* lds)
{
  constexpr int BUF = 2*128*SLDA;
  const int tid = threadIdx.x, lane = tid & 63, wid = tid >> 6;
  const int wr = (wid >> 1) * 64, wc = (wid & 1) * 64;
  const int lr16 = lane >> 2, lgrp = lane & 3;
  const int rA = wid*32 + lr16;
  const int sw = (rA >> 1) & 3;
  long a0, a1;
  if (GATHER) {
    int t0 = rowmap[m0 + rA];      if (t0 < 0) t0 = 0;
    int t1 = rowmap[m0 + rA + 16]; if (t1 < 0) t1 = 0;
    a0 = (long)t0 * lda + ((lgrp ^ sw) << 3);
    a1 = (long)t1 * lda + ((lgrp ^ sw) << 3);
  } else {
    a0 = (long)(m0 + rA)      * lda + ((lgrp ^ sw) << 3);
    a1 = (long)(m0 + rA + 16) * lda + ((lgrp ^ sw) << 3);
  }
  const long b0 = (long)(n0 + rA)      * ldb + ((lgrp ^ sw) << 3);
  const long b1 = (long)(n0 + rA + 16) * ldb + ((lgrp ^ sw) << 3);
  const int oR0 = (wid*32)*SLDA, oR1 = (wid*32+16)*SLDA;
  const int fr = lane & 15, gi = lane >> 4;
  const int pcol = ((gi ^ ((lane >> 1) & 3)) << 3);
  const int nt = K >> 5;

  auto stage = [&](int t, int buf) {
    h16* base = lds + buf*BUF;
    h16* sA = base;  h16* sB = base + 128*SLDA;
    const int k0 = t << 5;
    gload16(A + a0 + k0, sA + oR0);
    gload16(A + a1 + k0, sA + oR1);
    gload16(B + b0 + k0, sB + oR0);
    gload16(B + b1 + k0, sB + oR1);
  };

  stage(0, 0);
  __syncthreads();
  int cur = 0;
  for (int t = 0; t < nt; ++t) {
    if (t + 1 < nt) stage(t + 1, cur ^ 1);
    h16* base = lds + cur*BUF;
    h16* sA = base;  h16* sB = base + 128*SLDA;
    h16x8 a_[4], b_[4];
    #pragma unroll
    for (int i = 0; i < 4; ++i)
      a_[i] = *(const h16x8*)(sA + (wr + i*16 + fr)*SLDA + pcol);
    #pragma unroll
    for (int j = 0; j < 4; ++j)
      b_[j] = *(const h16x8*)(sB + (wc + j*16 + fr)*SLDA + pcol);
    #pragma unroll
    for (int i = 0; i < 4; ++i)
      #pragma unroll
      for (int j = 0; j < 4; ++j)
        acc[i][j] = MFMA16(a_[i], b_[j], acc[i][j]);
    __syncthreads();
    cur ^= 1;
  }
}

// ---------------------------------------------------------------------------
// prep kernels
// ---------------------------------------------------------------------------
__global__ void k_zero8(int* __restrict__ p) {
  if (threadIdx.x < 8) p[threadIdx.x] = 0;
}

__global__ void k_split_in(const float* __restrict__ src, const float* __restrict__ pos,
                           h16* __restrict__ qkH, h16* __restrict__ qkL,
                           h16* __restrict__ sH,  h16* __restrict__ sL) {
  int i = blockIdx.x*256 + threadIdx.x;
  float4 s = ((const float4*)src)[i];
  float4 p = ((const float4*)pos)[i];
  float sv[4] = {s.x, s.y, s.z, s.w};
  float qv[4] = {s.x+p.x, s.y+p.y, s.z+p.z, s.w+p.w};
  h16x4 sh, sl, qh, ql;
  #pragma unroll
  for (int q = 0; q < 4; ++q) {
    float xs = sv[q] * 16.0f; h16 hs = (h16)xs;
    sh[q] = hs; sl[q] = (h16)(xs - (float)hs);
    float xq = qv[q] * 16.0f; h16 hq = (h16)xq;
    qh[q] = hq; ql[q] = (h16)(xq - (float)hq);
  }
  ((h16x4*)sH)[i] = sh; ((h16x4*)sL)[i] = sl;
  ((h16x4*)qkH)[i] = qh; ((h16x4*)qkL)[i] = ql;
}

__global__ void k_split2(const float* __restrict__ a,
                         h16* __restrict__ H, h16* __restrict__ L, float scale, int n4) {
  int i = blockIdx.x*256 + threadIdx.x;
  if (i >= n4) return;
  float4 v = ((const float4*)a)[i];
  float vv[4] = {v.x, v.y, v.z, v.w};
  h16x4 hv, lv;
  #pragma unroll
  for (int q = 0; q < 4; ++q) {
    float x = vv[q] * scale;
    h16 h = (h16)x;
    hv[q] = h;
    lv[q] = (h16)(x - (float)h);
  }
  ((h16x4*)H)[i] = hv;
  ((h16x4*)L)[i] = lv;
}

__global__ void k_tof16(const float* __restrict__ a, h16* __restrict__ H, float scale, int n4) {
  int i = blockIdx.x*256 + threadIdx.x;
  if (i >= n4) return;
  float4 v = ((const float4*)a)[i];
  h16x4 hv;
  hv[0] = (h16)(v.x*scale); hv[1] = (h16)(v.y*scale);
  hv[2] = (h16)(v.z*scale); hv[3] = (h16)(v.w*scale);
  ((h16x4*)H)[i] = hv;
}

// ---------------------------------------------------------------------------
// QKV projection, 256x256 tile. Grid 384 = 8 XCD x (4 m-panels x 12 n).
// Each 256-col block is entirely Q (n0<1024), K (<2048) or V.
// ---------------------------------------------------------------------------
__global__ __launch_bounds__(512, 2) void k_qkv(
    const h16* __restrict__ qkh, const h16* __restrict__ qkl,
    const h16* __restrict__ sh,  const h16* __restrict__ sl,
    const h16* __restrict__ Wh,  const h16* __restrict__ Wl, const float* __restrict__ bias,
    h16* __restrict__ Qh, h16* __restrict__ Ql, h16* __restrict__ Kh, h16* __restrict__ Kl,
    h16* __restrict__ Vh, h16* __restrict__ Vl)
{
  __shared__ h16 lds[4*256*SLDA];   // 65,536 B single buffer
  const int bid = blockIdx.x;                       // 0..383
  const int xcd = bid & 7, loc = bid >> 3;          // loc 0..47
  const int m0 = (xcd*4 + (loc & 3)) * 256;
  const int n0 = (loc >> 2) * 256;
  const bool isV = (n0 >= 2048);
  f32x4 acc[8][4] = {};
  gemm256_core(isV ? sh : qkh, isV ? sl : qkl, Wh, Wl,
               1024, 1024, 1024, m0, n0, acc, lds);
  EPI_256;
  if (!isV) {
    const bool isK = (n0 >= 1024);
    h16* Hd = isK ? Kh : Qh;
    h16* Ld = isK ? Kl : Ql;
    #pragma unroll
    for (int i = 0; i < 8; ++i)
      #pragma unroll
      for (int j = 0; j < 4; ++j)
        #pragma unroll
        for (int r = 0; r < 4; ++r) {
          int row = m0 + wr + i*16 + rb + r;
          int col = n0 + wc + j*16 + fr;
          float c = acc[i][j][r] * (1.0f/1024.0f) + bias[col];
          int b = row >> 10, s = row & 1023;
          int cc = col & 1023, h = cc >> 6, d = cc & 63;
          long bh = (long)b*NH + h;
          store_split(Hd, Ld, (bh*SEQ + s)*HD + d, c * 16.0f);
        }
  } else {
    // V^T [bh][d][s]: pack 4 consecutive s (r-quad) into one 8B store
    #pragma unroll
    for (int i = 0; i < 8; ++i)
      #pragma unroll
      for (int j = 0; j < 4; ++j) {
        int row0 = m0 + wr + i*16 + rb;
        int col  = n0 + wc + j*16 + fr;
        int cc = col & 1023, h = cc >> 6, d = cc & 63;
        float bcol = bias[col];
        h16x4 hv, lv;
        #pragma unroll
        for (int r = 0; r < 4; ++r) {
          float cs = (acc[i][j][r] * (1.0f/1024.0f) + bcol) * 16.0f;
          h16 hh = (h16)cs;
          hv[r] = hh;
          lv[r] = (h16)(cs - (float)hh);
        }
        int b = row0 >> 10, s0 = row0 & 1023;
        long base = ((long)(b*NH + h)*HD + d)*SEQ + s0;
        *(h16x4*)(Vh + base) = hv;
        *(h16x4*)(Vl + base) = lv;
      }
  }
}

// ---------------------------------------------------------------------------
// Fused flash attention (round 12 structure, merged-format combines).
// ---------------------------------------------------------------------------
__global__ __launch_bounds__(256) void k_attn(
    const h16* __restrict__ Qh, const h16* __restrict__ Ql,
    const h16* __restrict__ Kh, const h16* __restrict__ Kl,
    const h16* __restrict__ Vh, const h16* __restrict__ Vl,
    h16* __restrict__ Oh, h16* __restrict__ Ol)
{
  __shared__ h16 lds[4*64*FLD];
  h16* sKh = lds;            h16* sKl = lds + 64*FLD;
  h16* sVh = lds + 2*64*FLD; h16* sVl = lds + 3*64*FLD;
  const int bid = blockIdx.x;
  const int swz = (bid & 7) * 256 + (bid >> 3);
  const int bh = swz >> 4;
  const int q0 = (swz & 15) * QB;
  const int tid = threadIdx.x, lane = tid & 63, w = tid >> 6;
  const int fr = lane & 15, hg = lane >> 4;
  const int kg = hg << 3;
  const long qbase = ((long)bh*SEQ + q0 + w*16 + fr) * HD;
  h16x8 qh[2], ql[2];
  qh[0] = *(const h16x8*)(Qh + qbase + kg);
  qh[1] = *(const h16x8*)(Qh + qbase + 32 + kg);
  ql[0] = *(const h16x8*)(Ql + qbase + kg);
  ql[1] = *(const h16x8*)(Ql + qbase + 32 + kg);
  f32x4 o1[4] = {}, o2[4] = {};
  float mrow = -3.0e38f, lrow = 0.f;
  const int srow = tid >> 2, skc = (tid & 3) << 4;
  const long kbase = ((long)bh*SEQ + srow) * HD + skc;
  const long vbase = ((long)bh*HD + srow) * SEQ + skc;
  const int srcA = fr + ((hg & 1) << 5);
  const int srcB = srcA + 16;
  for (int kt = 0; kt < NCHUNK; ++kt) {
    const int n0 = kt * QB;
    __syncthreads();
    {
      const long ka = kbase + (long)n0*HD;
      *(uint4*)(sKh + srow*FLD + skc)     = *(const uint4*)(Kh + ka);
      *(uint4*)(sKh + srow*FLD + skc + 8) = *(const uint4*)(Kh + ka + 8);
      *(uint4*)(sKl + srow*FLD + skc)     = *(const uint4*)(Kl + ka);
      *(uint4*)(sKl + srow*FLD + skc + 8) = *(const uint4*)(Kl + ka + 8);
      const long va = vbase + n0;
      *(uint4*)(sVh + srow*FLD + skc)     = *(const uint4*)(Vh + va);
      *(uint4*)(sVh + srow*FLD + skc + 8) = *(const uint4*)(Vh + va + 8);
      *(uint4*)(sVl + srow*FLD + skc)     = *(const uint4*)(Vl + va);
      *(uint4*)(sVl + srow*FLD + skc + 8) = *(const uint4*)(Vl + va + 8);
    }
    __syncthreads();
    f32x4 s1[4] = {}, s2[4] = {};
    #pragma unroll
    for (int ks = 0; ks < 2; ++ks)
      #pragma unroll
      for (int j = 0; j < 4; ++j) {
        h16x8 kh = *(const h16x8*)(sKh + (j*16 + fr)*FLD + ks*32 + kg);
        h16x8 kl = *(const h16x8*)(sKl + (j*16 + fr)*FLD + ks*32 + kg);
        s1[j] = MFMA16(kh, qh[ks], s1[j]);
        s2[j] = MFMA16(kh, ql[ks], s2[j]);
        s2[j] = MFMA16(kl, qh[ks], s2[j]);
      }
    float p[4][4];
    float tmax = -3.0e38f;
    #pragma unroll
    for (int j = 0; j < 4; ++j)
      #pragma unroll
      for (int r = 0; r < 4; ++r) {
        float sc = (s1[j][r] + s2[j][r]) * (0.125f/256.0f);
        p[j][r] = sc;
        tmax = fmaxf(tmax, sc);
      }
    tmax = fmaxf(tmax, __shfl_xor(tmax, 16));
    tmax = fmaxf(tmax, __shfl_xor(tmax, 32));
    float mn = fmaxf(mrow, tmax);
    float sclf = __expf(mrow - mn);
    mrow = mn;
    float psum = 0.f;
    #pragma unroll
    for (int j = 0; j < 4; ++j)
      #pragma unroll
      for (int r = 0; r < 4; ++r) { float e = __expf(p[j][r] - mn); p[j][r] = e; psum += e; }
    psum += __shfl_xor(psum, 16);
    psum += __shfl_xor(psum, 32);
    lrow = lrow*sclf + psum;
    #pragma unroll
    for (int r = 0; r < 4; ++r) {
      float sq = __shfl(sclf, hg*4 + r);
      #pragma unroll
      for (int jd = 0; jd < 4; ++jd) { o1[jd][r] *= sq; o2[jd][r] *= sq; }
    }
    u32 hp[4][2], lp[4][2];
    #pragma unroll
    for (int j = 0; j < 4; ++j)
      #pragma unroll
      for (int rp = 0; rp < 2; ++rp) {
        float a = p[j][2*rp]   * 512.0f;
        float b = p[j][2*rp+1] * 512.0f;
        float fa, fb;
        hp[j][rp] = pk2(a, b, fa, fb);
        lp[j][rp] = pk2w(a - fa, b - fb);
      }
    #pragma unroll
    for (int ks = 0; ks < 2; ++ks) {
      const int j0 = 2*ks, j1 = 2*ks + 1;
      u32 hA0 = (u32)__shfl((int)hp[j0][0], srcA), hA1 = (u32)__shfl((int)hp[j0][1], srcA);
      u32 hB0 = (u32)__shfl((int)hp[j0][0], srcB), hB1 = (u32)__shfl((int)hp[j0][1], srcB);
      u32 hC0 = (u32)__shfl((int)hp[j1][0], srcA), hC1 = (u32)__shfl((int)hp[j1][1], srcA);
      u32 hD0 = (u32)__shfl((int)hp[j1][0], srcB), hD1 = (u32)__shfl((int)hp[j1][1], srcB);
      u32 lA0 = (u32)__shfl((int)lp[j0][0], srcA), lA1 = (u32)__shfl((int)lp[j0][1], srcA);
      u32 lB0 = (u32)__shfl((int)lp[j0][0], srcB), lB1 = (u32)__shfl((int)lp[j0][1], srcB);
      u32 lC0 = (u32)__shfl((int)lp[j1][0], srcA), lC1 = (u32)__shfl((int)lp[j1][1], srcA);
      u32 lD0 = (u32)__shfl((int)lp[j1][0], srcB), lD1 = (u32)__shfl((int)lp[j1][1], srcB);
      const bool hij = (hg & 2) != 0;
      union { u32 w[4]; h16x8 v; } pa, pb;
      pa.w[0] = hij ? hC0 : hA0;  pa.w[1] = hij ? hC1 : hA1;
      pa.w[2] = hij ? hD0 : hB0;  pa.w[3] = hij ? hD1 : hB1;
      pb.w[0] = hij ? lC0 : lA0;  pb.w[1] = hij ? lC1 : lA1;
      pb.w[2] = hij ? lD0 : lB0;  pb.w[3] = hij ? lD1 : lB1;
      #pragma unroll
      for (int jd = 0; jd < 4; ++jd) {
        h16x8 vh = *(const h16x8*)(sVh + (jd*16 + fr)*FLD + ks*32 + kg);
        h16x8 vl = *(const h16x8*)(sVl + (jd*16 + fr)*FLD + ks*32 + kg);
        o1[jd] = MFMA16(pa.v, vh, o1[jd]);
        o2[jd] = MFMA16(pa.v, vl, o2[jd]);
        o2[jd] = MFMA16(pb.v, vh, o2[jd]);
      }
    }
  }
  float lq[4];
  #pragma unroll
  for (int r = 0; r < 4; ++r) lq[r] = __shfl(lrow, hg*4 + r);
  const int b = bh >> 4, h = bh & 15;
  #pragma unroll
  for (int jd = 0; jd < 4; ++jd)
    #pragma unroll
    for (int r = 0; r < 4; ++r) {
      int qrow = q0 + w*16 + hg*4 + r;
      int d = jd*16 + fr;
      float ov = (o1[jd][r] + o2[jd][r]) / (512.0f*16.0f*lq[r]);
      store_split(Oh, Ol, ((long)b*SEQ + qrow)*DM + h*HD + d, ov*16.0f);
    }
}

// out_proj: 256x256 tile. Grid 128 = 8 XCD x (4 m x 4 n).
__global__ __launch_bounds__(512, 2) void k_out(
    const h16* __restrict__ Oh, const h16* __restrict__ Ol,
    const h16* __restrict__ Wh, const h16* __restrict__ Wl,
    const float* __restrict__ bias, float* __restrict__ attn)
{
  __shared__ h16 lds[4*256*SLDA];
  const int bid = blockIdx.x;                       // 0..127
  const int xcd = bid & 7, loc = bid >> 3;          // loc 0..15
  const int m0 = (xcd*4 + (loc & 3)) * 256;
  const int n0 = (loc >> 2) * 256;
  f32x4 acc[8][4] = {};
  gemm256_core(Oh, Ol, Wh, Wl, 1024, 1024, 1024, m0, n0, acc, lds);
  EPI_256;
  #pragma unroll
  for (int i = 0; i < 8; ++i)
    #pragma unroll
    for (int j = 0; j < 4; ++j)
      #pragma unroll
      for (int r = 0; r < 4; ++r) {
        int row = m0 + wr + i*16 + rb + r;
        int col = n0 + wc + j*16 + fr;
        attn[(long)row*DM + col] = acc[i][j][r] * (1.0f/1024.0f) + bias[col];
      }
}

// LayerNorm of (A + Badd)
__global__ __launch_bounds__(256) void k_ln(
    const float* __restrict__ A, const float* __restrict__ Badd,
    const float* __restrict__ g, const float* __restrict__ be,
    float* __restrict__ xout, h16* __restrict__ xh, float* __restrict__ dout)
{
  int wave = threadIdx.x >> 6, lane = threadIdx.x & 63;
  long row = (long)blockIdx.x*4 + wave;
  const float* ar = A + row*DM; const float* br = Badd + row*DM;
  float v[16]; float s = 0.0f;
  #pragma unroll
  for (int p = 0; p < 4; ++p) {
    int d = p*256 + lane*4;
    float4 a = *(const float4*)(ar + d);
    float4 b = *(const float4*)(br + d);
    float t0=a.x+b.x, t1=a.y+b.y, t2=a.z+b.z, t3=a.w+b.w;
    v[4*p+0]=t0; v[4*p+1]=t1; v[4*p+2]=t2; v[4*p+3]=t3;
    s += t0+t1+t2+t3;
  }
  s = wave_sum(s);
  float m = s * (1.0f/1024.0f);
  float q = 0.0f;
  #pragma unroll
  for (int i = 0; i < 16; ++i) { float dd = v[i]-m; q += dd*dd; }
  q = wave_sum(q);
  float rs = (float)(1.0 / sqrt((double)(q * (1.0f/1024.0f) + 1e-5f)));
  #pragma unroll
  for (int p = 0; p < 4; ++p) {
    int d = p*256 + lane*4;
    float4 gv = *(const float4*)(g + d);
    float4 bv = *(const float4*)(be + d);
    float y0 = (v[4*p+0]-m)*rs*gv.x + bv.x;
    float y1 = (v[4*p+1]-m)*rs*gv.y + bv.y;
    float y2 = (v[4*p+2]-m)*rs*gv.z + bv.z;
    float y3 = (v[4*p+3]-m)*rs*gv.w + bv.w;
    if (xout) { float4 o = {y0,y1,y2,y3}; *(float4*)(xout + row*DM + d) = o; }
    if (xh) {
      h16x4 hv; hv[0]=(h16)(y0*16.f); hv[1]=(h16)(y1*16.f);
      hv[2]=(h16)(y2*16.f); hv[3]=(h16)(y3*16.f);
      *(h16x4*)(xh + row*DM + d) = hv;
    }
    if (dout) { float4 o = {y0,y1,y2,y3}; *(float4*)(dout + row*DM + d) = o; }
  }
}

// ---------------------------------------------------------------------------
// threefry2x32 (key=[0,42]) -> gumbel -> argmax. VERIFIED round 5 — DO NOT TOUCH.
// ---------------------------------------------------------------------------
__device__ __forceinline__ void threefry(u32 x0, u32 x1, u32& y0, u32& y1) {
  const u32 ks0 = 0u, ks1 = 42u, ks2 = 0x1BD11BDAu ^ 42u;
  x0 += ks0; x1 += ks1;
  #define TF_R(r) { x0 += x1; x1 = (x1 << r) | (x1 >> (32 - r)); x1 ^= x0; }
  TF_R(13) TF_R(15) TF_R(26) TF_R(6)  x0 += ks1; x1 += ks2 + 1u;
  TF_R(17) TF_R(29) TF_R(16) TF_R(24) x0 += ks2; x1 += ks0 + 2u;
  TF_R(13) TF_R(15) TF_R(26) TF_R(6)  x0 += ks0; x1 += ks1 + 3u;
  TF_R(17) TF_R(29) TF_R(16) TF_R(24) x0 += ks1; x1 += ks2 + 4u;
  TF_R(13) TF_R(15) TF_R(26) TF_R(6)  x0 += ks2; x1 += ks0 + 5u;
  #undef TF_R
  y0 = x0; y1 = x1;
}

__device__ __forceinline__ float gumbel_from(u32 bits) {
  float f = __uint_as_float((bits >> 9) | 0x3F800000u) - 1.0f;
  float u = (f > 0.0f) ? f : 1.17549435e-38f;
  float nl = (float)(-log((double)u));
  return -(float)log((double)nl);
}

__global__ __launch_bounds__(256) void k_gate(
    const float* __restrict__ x, const float* __restrict__ gw,
    const float* __restrict__ gb, int* __restrict__ chosen, int* __restrict__ counts)
{
  int wave = threadIdx.x >> 6, lane = threadIdx.x & 63;
  long t = (long)blockIdx.x*4 + wave;
  const float* xr = x + t*DM;
  float p[4] = {0.f,0.f,0.f,0.f};
  #pragma unroll
  for (int pp = 0; pp < 4; ++pp) {
    int d = pp*256 + lane*4;
    float4 xv = *(const float4*)(xr + d);
    #pragma unroll
    for (int e = 0; e < 4; ++e) {
      float4 gv = *(const float4*)(gw + e*DM + d);
      p[e] += xv.x*gv.x + xv.y*gv.y + xv.z*gv.z + xv.w*gv.w;
    }
  }
  #pragma unroll
  for (int e = 0; e < 4; ++e) p[e] = wave_sum(p[e]);
  if (lane == 0) {
    float best = -3.0e38f; int arg = 0;
    #pragma unroll
    for (int e = 0; e < 4; ++e) {
      float logit = p[e] + gb[e];
      u32 j = (u32)(4*t + e);
      u32 y0, y1;
      threefry(0u, j, y0, y1);
      float v = gumbel_from(y0 ^ y1) + logit;
      if (v > best) { best = v; arg = e; }
    }
    chosen[(int)t] = arg;
    atomicAdd(&counts[arg], 1);
  }
}

__global__ void k_offsets(const int* __restrict__ counts, int* __restrict__ eoff) {
  if (threadIdx.x == 0 && blockIdx.x == 0) {
    int o = 0;
    for (int e = 0; e < 4; ++e) { eoff[e] = o; o += (counts[e] + 127) & ~127; }
  }
}

__global__ void k_fill(int* __restrict__ p, int n) {
  int i = blockIdx.x*256 + threadIdx.x;
  if (i < n) p[i] = -1;
}

__global__ void k_scatter(const int* __restrict__ chosen, const int* __restrict__ eoff,
                          int* __restrict__ cursor, int* __restrict__ plist) {
  int t = blockIdx.x*256 + threadIdx.x;
  if (t >= BS) return;
  int e = chosen[t];
  int slot = atomicAdd(&cursor[e], 1);
  plist[eoff[e] + slot] = t;
}

// MoE layer 1 (gathered rows, 128x128 dbuf core)
__global__ __launch_bounds__(256) void k_e1(
    const h16* __restrict__ Xh, const h16* __restrict__ W1, const float* __restrict__ b1,
    const int* __restrict__ plist, const int* __restrict__ eoff, h16* __restrict__ Hh)
{
  __shared__ h16 lds[2*2*128*SLDA];
  const int n0 = blockIdx.x*128, m0 = blockIdx.y*128;
  const int e = (m0 >= eoff[1]) + (m0 >= eoff[2]) + (m0 >= eoff[3]);
  f32x4 acc[4][4] = {};
  hgemm128x128_core<true>(Xh, W1 + (long)e*DFE*DM, 1024, 1024, 1024, m0, n0, plist, acc, lds);
  EPI_X;
  #pragma unroll
  for (int i = 0; i < 4; ++i)
    #pragma unroll
    for (int j = 0; j < 4; ++j)
      #pragma unroll
      for (int r = 0; r < 4; ++r) {
        int row = m0 + wr + i*16 + rb + r;
        int col = n0 + wc + j*16 + fr;
        float c = acc[i][j][r] * (1.0f/1024.0f) + b1[e*DFE + col];
        c = fmaxf(c, 0.0f);
        Hh[(long)row*DFE + col] = (h16)(c * 16.0f);
      }
}

// MoE layer 2 (bucket rows, scatter out)
__global__ __launch_bounds__(256) void k_e2(
    const h16* __restrict__ Hh, const h16* __restrict__ W2, const float* __restrict__ b2,
    const int* __restrict__ plist, const int* __restrict__ eoff, float* __restrict__ y)
{
  __shared__ h16 lds[2*2*128*SLDA];
  const int n0 = blockIdx.x*128, m0 = blockIdx.y*128;
  const int e = (m0 >= eoff[1]) + (m0 >= eoff[2]) + (m0 >= eoff[3]);
  f32x4 acc[4][4] = {};
  hgemm128x128_core<false>(Hh, W2 + (long)e*DM*DFE, 1024, DFE, DFE, m0, n0, nullptr, acc, lds);
  EPI_X;
  #pragma unroll
  for (int i = 0; i < 4; ++i)
    #pragma unroll
    for (int j = 0; j < 4; ++j)
      #pragma unroll
      for (int r = 0; r < 4; ++r) {
        int row = m0 + wr + i*16 + rb + r;
        int col = n0 + wc + j*16 + fr;
        int t = plist[row];
        if (t >= 0)
          y[(long)t*DM + col] = acc[i][j][r] * (1.0f/1024.0f) + b2[e*DM + col];
      }
}

// ---------------------------------------------------------------------------
extern "C" void kernel_launch(void* const* d_in, const int* in_sizes, int n_in,
                              void* d_out, int out_size, void* d_ws, size_t ws_size,
                              hipStream_t stream) {
  const float* src = (const float*)d_in[0];
  const float* pos = (const float*)d_in[1];
  const float* w3  = (const float*)d_in[2];
  const float* b3  = (const float*)d_in[3];
  const float* wo  = (const float*)d_in[4];
  const float* bo  = (const float*)d_in[5];
  const float* gw  = (const float*)d_in[6];
  const float* gb  = (const float*)d_in[7];
  const float* w1  = (const float*)d_in[8];
  const float* b1  = (const float*)d_in[9];
  const float* w2  = (const float*)d_in[10];
  const float* b2  = (const float*)d_in[11];
  const float* g1  = (const float*)d_in[12];
  const float* be1 = (const float*)d_in[13];
  const float* g2  = (const float*)d_in[14];
  const float* be2 = (const float*)d_in[15];
  float* out = (float*)d_out;
  char* ws = (char*)d_ws;
  if (ws_size < WS_NEEDED) return;

  auto H = [&](size_t off) { return (h16*)(ws + off); };
  auto F = [&](size_t off) { return (float*)(ws + off); };
  auto I = [&](size_t off) { return (int*)(ws + off); };

  k_zero8<<<1, 64, 0, stream>>>(I(OFF_COUNTS));

  // input + weight splits (merged lo format)
  k_split_in<<<BS*DM/4/256, 256, 0, stream>>>(src, pos,
      H(OFF_QKH), H(OFF_QKL), H(OFF_SRCH), H(OFF_SRCL));
  k_split2<<<3*DM*DM/4/256, 256, 0, stream>>>(w3, H(OFF_W3H), H(OFF_W3L), 64.0f, 3*DM*DM/4);
  k_split2<<<DM*DM/4/256, 256, 0, stream>>>(wo, H(OFF_WOH), H(OFF_WOL), 64.0f, DM*DM/4);

  // QKV projection (256^2 tile, m-fast XCD mapping)
  k_qkv<<<dim3(384), 512, 0, stream>>>(
      H(OFF_QKH), H(OFF_QKL), H(OFF_SRCH), H(OFF_SRCL), H(OFF_W3H), H(OFF_W3L), b3,
      H(OFF_QH), H(OFF_QL), H(OFF_KH), H(OFF_KL), H(OFF_VH), H(OFF_VL));

  // fused flash attention
  k_attn<<<dim3(NCHUNK*NBH), 256, 0, stream>>>(
      H(OFF_QH), H(OFF_QL), H(OFF_KH), H(OFF_KL), H(OFF_VH), H(OFF_VL),
      H(OFF_OH), H(OFF_OL));

  // out projection + LN1
  k_out<<<dim3(128), 512, 0, stream>>>(
      H(OFF_OH), H(OFF_OL), H(OFF_WOH), H(OFF_WOL), bo, F(OFF_ATT));
  k_ln<<<BS/4, 256, 0, stream>>>(src, F(OFF_ATT), g1, be1, F(OFF_X), H(OFF_XH), nullptr);

  // gate + expert bucketing
  k_gate<<<BS/4, 256, 0, stream>>>(F(OFF_X), gw, gb, I(OFF_CHOSEN), I(OFF_COUNTS));
  k_offsets<<<1, 64, 0, stream>>>(I(OFF_COUNTS), I(OFF_EOFF));
  k_fill<<<(NPOS+255)/256, 256, 0, stream>>>(I(OFF_PLIST), NPOS);
  k_scatter<<<BS/256, 256, 0, stream>>>(I(OFF_CHOSEN), I(OFF_EOFF), I(OFF_CURSOR), I(OFF_PLIST));

  // MoE
  k_tof16<<<NE*DFE*DM/4/256, 256, 0, stream>>>(w1, H(OFF_W1H), 64.0f, NE*DFE*DM/4);
  k_tof16<<<NE*DM*DFE/4/256, 256, 0, stream>>>(w2, H(OFF_W2H), 64.0f, NE*DM*DFE/4);
  k_e1<<<dim3(DFE/128, NPOS/128), 256, 0, stream>>>(
      H(OFF_XH), H(OFF_W1H), b1, I(OFF_PLIST), I(OFF_EOFF), H(OFF_HH));
  k_e2<<<dim3(DM/128, NPOS/128), 256, 0, stream>>>(
      H(OFF_HH), H(OFF_W2H), b2, I(OFF_PLIST), I(OFF_EOFF), F(OFF_Y));

  // final LN2 -> output
  k_ln<<<BS/4, 256, 0, stream>>>(F(OFF_X), F(OFF_Y), g2, be2, nullptr, nullptr, out);
}